// Round 1
// baseline (3350.098 us; speedup 1.0000x reference)
//
#include <hip/hip_runtime.h>

// RGCN embedding, MI355X. Pipeline:
//   memset(deg,h1) -> build w1T/w2T (bf16) -> deg count -> out=bias2
//   -> GEMM1: xw[N][1024]=emb@w1T (bf16 MFMA) -> edge1 scatter h1 (f32 atomics)
//   -> relu+cast h1b -> GEMM2: z[N][512]=h1b@w2T (aliases xw) -> edge2 scatter out
#define N_NODES 100000
#define E_EDGES 3200000

typedef float f32x4 __attribute__((ext_vector_type(4)));
typedef __bf16 bf16x8 __attribute__((ext_vector_type(8)));

__device__ __forceinline__ float b2f(unsigned int u) {
    union { unsigned int i; float f; } x; x.i = u << 16; return x.f;
}
__device__ __forceinline__ unsigned short f2b(float f) {
    union { float f; unsigned int i; } x; x.f = f;
    unsigned int u = x.i + 0x7FFFu + ((x.i >> 16) & 1u);
    return (unsigned short)(u >> 16);
}

// w1T[j][k] = sum_b comps1[r,b]*bases1[b,k,h], j=r*32+h  (bf16, [1024][128])
__global__ __launch_bounds__(256) void kw1(const float* __restrict__ comps1,
                                           const float* __restrict__ bases1,
                                           unsigned short* __restrict__ w1T) {
    int id = blockIdx.x * 256 + threadIdx.x;
    if (id >= 1024 * 128) return;
    int k = id & 127, j = id >> 7;
    int r = j >> 5, h = j & 31;
    float s = 0.f;
#pragma unroll
    for (int b = 0; b < 16; b++)
        s += comps1[r * 16 + b] * bases1[b * 4096 + k * 32 + h];
    w1T[(size_t)j * 128 + k] = f2b(s);
}

// w2T[j2][h] = sum_b comps2[r,b]*bases2[b,h,c], j2=r*16+c  (bf16, [512][32])
__global__ __launch_bounds__(256) void kw2(const float* __restrict__ comps2,
                                           const float* __restrict__ bases2,
                                           unsigned short* __restrict__ w2T) {
    int id = blockIdx.x * 256 + threadIdx.x;
    if (id >= 512 * 32) return;
    int h = id & 31, j = id >> 5;
    int r = j >> 4, c = j & 15;
    float s = 0.f;
#pragma unroll
    for (int b = 0; b < 16; b++)
        s += comps2[r * 16 + b] * bases2[b * 512 + h * 16 + c];
    w2T[(size_t)j * 32 + h] = f2b(s);
}

__global__ __launch_bounds__(256) void kdeg(const int* __restrict__ rel,
                                            const int* __restrict__ fr,
                                            float* __restrict__ deg) {
    int e = blockIdx.x * 256 + threadIdx.x;
    if (e >= E_EDGES) return;
    atomicAdd(deg + (size_t)rel[e] * N_NODES + fr[e], 1.0f);
}

__global__ __launch_bounds__(256) void koutinit(const float* __restrict__ bias2,
                                                float* __restrict__ out) {
    int id = blockIdx.x * 256 + threadIdx.x;
    if (id >= N_NODES * 16) return;
    out[id] = bias2[id & 15];
}

// GEMM1: xw[m][j] = sum_k emb[m][k]*w1T[j][k].  M=100000,N'=1024,K=128.
// Block 256 thr = 4 waves (2x2 of 64x64), tile 128x128. A staged via LDS
// (f32->bf16 inline, 272B row stride: read/write at b128 bank floor).
// B (w1T, 256KB) read direct from global (L2-resident).
__global__ __launch_bounds__(256) void gemm1(const float* __restrict__ emb,
                                             const unsigned short* __restrict__ w1T,
                                             unsigned short* __restrict__ xw, int M) {
    __shared__ unsigned short As[128 * 136];
    int tid = threadIdx.x;
    int bn = blockIdx.x;            // 0..7 (fastest -> 8 blocks share A tile)
    int m0 = blockIdx.y * 128;
#pragma unroll
    for (int i = 0; i < 16; i++) {
        int idx = tid + i * 256;    // 4096 chunks of 4 f32
        int row = idx >> 5, ch = idx & 31;
        int gr = m0 + row;
        float4 v = make_float4(0.f, 0.f, 0.f, 0.f);
        if (gr < M) v = *(const float4*)(emb + (size_t)gr * 128 + ch * 4);
        ushort4 b;
        b.x = f2b(v.x); b.y = f2b(v.y); b.z = f2b(v.z); b.w = f2b(v.w);
        *(ushort4*)(&As[row * 136 + ch * 4]) = b;
    }
    __syncthreads();
    int lane = tid & 63, wave = tid >> 6;
    int wm = (wave & 1) * 64, wn = (wave >> 1) * 64;
    int m_ = lane & 15, q = lane >> 4;
    f32x4 acc[4][4] = {};
    const unsigned short* Bbase = w1T + (size_t)(bn * 128 + wn) * 128;
#pragma unroll
    for (int k0 = 0; k0 < 128; k0 += 32) {
        bf16x8 a[4], b[4];
#pragma unroll
        for (int i = 0; i < 4; i++)
            a[i] = *(const bf16x8*)(&As[(wm + i * 16 + m_) * 136 + k0 + q * 8]);
#pragma unroll
        for (int j = 0; j < 4; j++)
            b[j] = *(const bf16x8*)(Bbase + (size_t)(j * 16 + m_) * 128 + k0 + q * 8);
#pragma unroll
        for (int i = 0; i < 4; i++)
#pragma unroll
            for (int j = 0; j < 4; j++)
                acc[i][j] = __builtin_amdgcn_mfma_f32_16x16x32_bf16(a[i], b[j], acc[i][j], 0, 0, 0);
    }
#pragma unroll
    for (int i = 0; i < 4; i++)
#pragma unroll
        for (int rg = 0; rg < 4; rg++) {
            int grow = m0 + wm + i * 16 + q * 4 + rg;
            if (grow < M) {
#pragma unroll
                for (int j = 0; j < 4; j++) {
                    int gcol = bn * 128 + wn + j * 16 + m_;
                    xw[(size_t)grow * 1024 + gcol] = f2b(acc[i][j][rg]);
                }
            }
        }
}

// edge1: hidden1[fr] += (1/deg[seg]) * xw[to, rel*32 : rel*32+32].  4 lanes/edge.
__global__ __launch_bounds__(256) void edge1(const int* __restrict__ rel,
                                             const int* __restrict__ fr,
                                             const int* __restrict__ to,
                                             const float* __restrict__ deg,
                                             const unsigned short* __restrict__ xw,
                                             float* __restrict__ hidden1) {
    int t = blockIdx.x * 256 + threadIdx.x;
    int e = t >> 2;
    if (e >= E_EDGES) return;
    int p = t & 3;
    int r = rel[e], f = fr[e], u = to[e];
    float v = 1.0f / deg[(size_t)r * N_NODES + f];
    uint4 raw = *(const uint4*)(xw + (size_t)u * 1024 + (r << 5) + (p << 3));
    float* h = hidden1 + ((size_t)f << 5) + (p << 3);
    atomicAdd(h + 0, v * b2f(raw.x & 0xFFFFu));
    atomicAdd(h + 1, v * b2f(raw.x >> 16));
    atomicAdd(h + 2, v * b2f(raw.y & 0xFFFFu));
    atomicAdd(h + 3, v * b2f(raw.y >> 16));
    atomicAdd(h + 4, v * b2f(raw.z & 0xFFFFu));
    atomicAdd(h + 5, v * b2f(raw.z >> 16));
    atomicAdd(h + 6, v * b2f(raw.w & 0xFFFFu));
    atomicAdd(h + 7, v * b2f(raw.w >> 16));
}

__global__ __launch_bounds__(256) void krelu(const float* __restrict__ hidden1,
                                             const float* __restrict__ bias1,
                                             unsigned short* __restrict__ h1b) {
    int id = blockIdx.x * 256 + threadIdx.x;
    if (id >= N_NODES * 32) return;
    float x = hidden1[id] + bias1[id & 31];
    h1b[id] = f2b(fmaxf(x, 0.f));
}

// GEMM2: z[m][j2] = sum_h h1b[m][h]*w2T[j2][h].  M=100000,N'=512,K=32 (1 MFMA step).
__global__ __launch_bounds__(256) void gemm2(const unsigned short* __restrict__ h1b,
                                             const unsigned short* __restrict__ w2T,
                                             unsigned short* __restrict__ z, int M) {
    __shared__ unsigned short As[128 * 40];
    int tid = threadIdx.x;
    int bn = blockIdx.x;            // 0..3
    int m0 = blockIdx.y * 128;
#pragma unroll
    for (int i = 0; i < 2; i++) {
        int idx = tid + i * 256;    // 512 chunks of 8 bf16
        int row = idx >> 2, ch = idx & 3;
        int gr = m0 + row;
        uint4 v = make_uint4(0u, 0u, 0u, 0u);
        if (gr < M) v = *(const uint4*)(h1b + (size_t)gr * 32 + ch * 8);
        *(uint4*)(&As[row * 40 + ch * 8]) = v;
    }
    __syncthreads();
    int lane = tid & 63, wave = tid >> 6;
    int wm = (wave & 1) * 64, wn = (wave >> 1) * 64;
    int m_ = lane & 15, q = lane >> 4;
    f32x4 acc[4][4] = {};
    const unsigned short* Bbase = w2T + (size_t)(bn * 128 + wn) * 32;
    bf16x8 a[4], b[4];
#pragma unroll
    for (int i = 0; i < 4; i++)
        a[i] = *(const bf16x8*)(&As[(wm + i * 16 + m_) * 40 + q * 8]);
#pragma unroll
    for (int j = 0; j < 4; j++)
        b[j] = *(const bf16x8*)(Bbase + (size_t)(j * 16 + m_) * 32 + q * 8);
#pragma unroll
    for (int i = 0; i < 4; i++)
#pragma unroll
        for (int j = 0; j < 4; j++)
            acc[i][j] = __builtin_amdgcn_mfma_f32_16x16x32_bf16(a[i], b[j], acc[i][j], 0, 0, 0);
#pragma unroll
    for (int i = 0; i < 4; i++)
#pragma unroll
        for (int rg = 0; rg < 4; rg++) {
            int grow = m0 + wm + i * 16 + q * 4 + rg;
            if (grow < M) {
#pragma unroll
                for (int j = 0; j < 4; j++) {
                    int gcol = bn * 128 + wn + j * 16 + m_;
                    z[(size_t)grow * 512 + gcol] = f2b(acc[i][j][rg]);
                }
            }
        }
}

// edge2: out[fr][c] += (1/deg[seg]) * z[to, rel*16+c].  16 lanes/edge.
__global__ __launch_bounds__(256) void edge2(const int* __restrict__ rel,
                                             const int* __restrict__ fr,
                                             const int* __restrict__ to,
                                             const float* __restrict__ deg,
                                             const unsigned short* __restrict__ z,
                                             float* __restrict__ out) {
    int t = blockIdx.x * 256 + threadIdx.x;
    int e = t >> 4;
    if (e >= E_EDGES) return;
    int c = t & 15;
    int r = rel[e], f = fr[e], u = to[e];
    float v = 1.0f / deg[(size_t)r * N_NODES + f];
    float zz = b2f((unsigned int)z[(size_t)u * 512 + (r << 4) + c]);
    atomicAdd(out + (size_t)f * 16 + c, v * zz);
}

extern "C" void kernel_launch(void* const* d_in, const int* in_sizes, int n_in,
                              void* d_out, int out_size, void* d_ws, size_t ws_size,
                              hipStream_t stream) {
    (void)in_sizes; (void)n_in; (void)out_size; (void)ws_size;
    const float* emb    = (const float*)d_in[0];
    const float* comps1 = (const float*)d_in[1];
    const float* bases1 = (const float*)d_in[2];
    const float* comps2 = (const float*)d_in[3];
    const float* bases2 = (const float*)d_in[4];
    const float* bias1  = (const float*)d_in[5];
    const float* bias2  = (const float*)d_in[6];
    const int* rel = (const int*)d_in[7];
    const int* fr  = (const int*)d_in[8];
    const int* to  = (const int*)d_in[9];
    float* out = (float*)d_out;
    char* ws = (char*)d_ws;

    // workspace layout (all 256B-aligned offsets); total ~237.1 MB
    float* deg            = (float*)(ws);                    // 12.8 MB
    float* hidden1        = (float*)(ws + 12800000);         // 12.8 MB
    unsigned short* h1b   = (unsigned short*)(ws + 25600000);// 6.4 MB
    unsigned short* w1T   = (unsigned short*)(ws + 32000000);// 256 KB
    unsigned short* w2T   = (unsigned short*)(ws + 32262144);// 32 KB
    unsigned short* xw    = (unsigned short*)(ws + 32294912);// 204.8 MB
    unsigned short* z     = xw;  // alias: xw dead after edge1, z written by gemm2

    hipMemsetAsync(deg, 0, 25600000, stream);  // deg + hidden1 (adjacent)
    kw1<<<512, 256, 0, stream>>>(comps1, bases1, w1T);
    kw2<<<64, 256, 0, stream>>>(comps2, bases2, w2T);
    kdeg<<<12500, 256, 0, stream>>>(rel, fr, deg);
    koutinit<<<6250, 256, 0, stream>>>(bias2, out);
    gemm1<<<dim3(8, 782), 256, 0, stream>>>(emb, w1T, xw, N_NODES);
    edge1<<<50000, 256, 0, stream>>>(rel, fr, to, deg, xw, hidden1);
    krelu<<<12500, 256, 0, stream>>>(hidden1, bias1, h1b);
    gemm2<<<dim3(4, 782), 256, 0, stream>>>(h1b, w2T, z, N_NODES);
    edge2<<<200000, 256, 0, stream>>>(rel, fr, to, deg, z, out);
}

// Round 2
// 1027.579 us; speedup vs baseline: 3.2602x; 3.2602x over previous
//
#include <hip/hip_runtime.h>

// RGCN embedding, MI355X. Pipeline:
//   memset(deg,h1) -> build w1T/w2T (bf16) -> deg count -> out=bias2
//   -> GEMM1: xw[N][1024]=emb@w1T (bf16 MFMA) -> edge1 scatter h1 (f32 atomics)
//   -> relu+cast h1b -> GEMM2: z[N][512]=h1b@w2T (aliases xw) -> edge2 scatter out
//
// R2 change: edge1 now uses 32 lanes/edge with ONE atomicAdd per lane, so each
// edge's 128B destination line (hidden1[f*32..+31]) is covered by a single
// wave-instruction -> 1 fabric line-op/edge instead of 8 (WRITE_SIZE 3.28GB->0.41GB).
#define N_NODES 100000
#define E_EDGES 3200000

typedef float f32x4 __attribute__((ext_vector_type(4)));
typedef __bf16 bf16x8 __attribute__((ext_vector_type(8)));

__device__ __forceinline__ float b2f(unsigned int u) {
    union { unsigned int i; float f; } x; x.i = u << 16; return x.f;
}
__device__ __forceinline__ unsigned short f2b(float f) {
    union { float f; unsigned int i; } x; x.f = f;
    unsigned int u = x.i + 0x7FFFu + ((x.i >> 16) & 1u);
    return (unsigned short)(u >> 16);
}

// w1T[j][k] = sum_b comps1[r,b]*bases1[b,k,h], j=r*32+h  (bf16, [1024][128])
__global__ __launch_bounds__(256) void kw1(const float* __restrict__ comps1,
                                           const float* __restrict__ bases1,
                                           unsigned short* __restrict__ w1T) {
    int id = blockIdx.x * 256 + threadIdx.x;
    if (id >= 1024 * 128) return;
    int k = id & 127, j = id >> 7;
    int r = j >> 5, h = j & 31;
    float s = 0.f;
#pragma unroll
    for (int b = 0; b < 16; b++)
        s += comps1[r * 16 + b] * bases1[b * 4096 + k * 32 + h];
    w1T[(size_t)j * 128 + k] = f2b(s);
}

// w2T[j2][h] = sum_b comps2[r,b]*bases2[b,h,c], j2=r*16+c  (bf16, [512][32])
__global__ __launch_bounds__(256) void kw2(const float* __restrict__ comps2,
                                           const float* __restrict__ bases2,
                                           unsigned short* __restrict__ w2T) {
    int id = blockIdx.x * 256 + threadIdx.x;
    if (id >= 512 * 32) return;
    int h = id & 31, j = id >> 5;
    int r = j >> 4, c = j & 15;
    float s = 0.f;
#pragma unroll
    for (int b = 0; b < 16; b++)
        s += comps2[r * 16 + b] * bases2[b * 512 + h * 16 + c];
    w2T[(size_t)j * 32 + h] = f2b(s);
}

__global__ __launch_bounds__(256) void kdeg(const int* __restrict__ rel,
                                            const int* __restrict__ fr,
                                            float* __restrict__ deg) {
    int e = blockIdx.x * 256 + threadIdx.x;
    if (e >= E_EDGES) return;
    atomicAdd(deg + (size_t)rel[e] * N_NODES + fr[e], 1.0f);
}

__global__ __launch_bounds__(256) void koutinit(const float* __restrict__ bias2,
                                                float* __restrict__ out) {
    int id = blockIdx.x * 256 + threadIdx.x;
    if (id >= N_NODES * 16) return;
    out[id] = bias2[id & 15];
}

// GEMM1: xw[m][j] = sum_k emb[m][k]*w1T[j][k].  M=100000,N'=1024,K=128.
__global__ __launch_bounds__(256) void gemm1(const float* __restrict__ emb,
                                             const unsigned short* __restrict__ w1T,
                                             unsigned short* __restrict__ xw, int M) {
    __shared__ unsigned short As[128 * 136];
    int tid = threadIdx.x;
    int bn = blockIdx.x;            // 0..7 (8 blocks share an A tile)
    int m0 = blockIdx.y * 128;
#pragma unroll
    for (int i = 0; i < 16; i++) {
        int idx = tid + i * 256;    // 4096 chunks of 4 f32
        int row = idx >> 5, ch = idx & 31;
        int gr = m0 + row;
        float4 v = make_float4(0.f, 0.f, 0.f, 0.f);
        if (gr < M) v = *(const float4*)(emb + (size_t)gr * 128 + ch * 4);
        ushort4 b;
        b.x = f2b(v.x); b.y = f2b(v.y); b.z = f2b(v.z); b.w = f2b(v.w);
        *(ushort4*)(&As[row * 136 + ch * 4]) = b;
    }
    __syncthreads();
    int lane = tid & 63, wave = tid >> 6;
    int wm = (wave & 1) * 64, wn = (wave >> 1) * 64;
    int m_ = lane & 15, q = lane >> 4;
    f32x4 acc[4][4] = {};
    const unsigned short* Bbase = w1T + (size_t)(bn * 128 + wn) * 128;
#pragma unroll
    for (int k0 = 0; k0 < 128; k0 += 32) {
        bf16x8 a[4], b[4];
#pragma unroll
        for (int i = 0; i < 4; i++)
            a[i] = *(const bf16x8*)(&As[(wm + i * 16 + m_) * 136 + k0 + q * 8]);
#pragma unroll
        for (int j = 0; j < 4; j++)
            b[j] = *(const bf16x8*)(Bbase + (size_t)(j * 16 + m_) * 128 + k0 + q * 8);
#pragma unroll
        for (int i = 0; i < 4; i++)
#pragma unroll
            for (int j = 0; j < 4; j++)
                acc[i][j] = __builtin_amdgcn_mfma_f32_16x16x32_bf16(a[i], b[j], acc[i][j], 0, 0, 0);
    }
#pragma unroll
    for (int i = 0; i < 4; i++)
#pragma unroll
        for (int rg = 0; rg < 4; rg++) {
            int grow = m0 + wm + i * 16 + q * 4 + rg;
            if (grow < M) {
#pragma unroll
                for (int j = 0; j < 4; j++) {
                    int gcol = bn * 128 + wn + j * 16 + m_;
                    xw[(size_t)grow * 1024 + gcol] = f2b(acc[i][j][rg]);
                }
            }
        }
}

// edge1: hidden1[fr][h] += (1/deg[seg]) * xw[to, rel*32+h].  32 lanes/edge,
// ONE atomic per lane -> the 32 same-line lanes coalesce to ~1 fabric line-op/edge.
__global__ __launch_bounds__(256) void edge1(const int* __restrict__ rel,
                                             const int* __restrict__ fr,
                                             const int* __restrict__ to,
                                             const float* __restrict__ deg,
                                             const unsigned short* __restrict__ xw,
                                             float* __restrict__ hidden1) {
    long long t = (long long)blockIdx.x * 256 + threadIdx.x;
    int e = (int)(t >> 5);
    if (e >= E_EDGES) return;
    int h = (int)t & 31;
    int r = rel[e], f = fr[e], u = to[e];
    float v = 1.0f / deg[(size_t)r * N_NODES + f];
    float x = b2f((unsigned int)xw[(size_t)u * 1024 + (r << 5) + h]);
    atomicAdd(hidden1 + ((size_t)f << 5) + h, v * x);
}

__global__ __launch_bounds__(256) void krelu(const float* __restrict__ hidden1,
                                             const float* __restrict__ bias1,
                                             unsigned short* __restrict__ h1b) {
    int id = blockIdx.x * 256 + threadIdx.x;
    if (id >= N_NODES * 32) return;
    float x = hidden1[id] + bias1[id & 31];
    h1b[id] = f2b(fmaxf(x, 0.f));
}

// GEMM2: z[m][j2] = sum_h h1b[m][h]*w2T[j2][h].  M=100000,N'=512,K=32 (1 MFMA step).
__global__ __launch_bounds__(256) void gemm2(const unsigned short* __restrict__ h1b,
                                             const unsigned short* __restrict__ w2T,
                                             unsigned short* __restrict__ z, int M) {
    __shared__ unsigned short As[128 * 40];
    int tid = threadIdx.x;
    int bn = blockIdx.x;            // 0..3
    int m0 = blockIdx.y * 128;
#pragma unroll
    for (int i = 0; i < 2; i++) {
        int idx = tid + i * 256;    // 512 chunks of 8 bf16
        int row = idx >> 2, ch = idx & 3;
        int gr = m0 + row;
        uint4 v = make_uint4(0u, 0u, 0u, 0u);
        if (gr < M) v = *(const uint4*)(h1b + (size_t)gr * 32 + ch * 8);
        *(uint4*)(&As[row * 40 + ch * 8]) = v;
    }
    __syncthreads();
    int lane = tid & 63, wave = tid >> 6;
    int wm = (wave & 1) * 64, wn = (wave >> 1) * 64;
    int m_ = lane & 15, q = lane >> 4;
    f32x4 acc[4][4] = {};
    const unsigned short* Bbase = w2T + (size_t)(bn * 128 + wn) * 32;
    bf16x8 a[4], b[4];
#pragma unroll
    for (int i = 0; i < 4; i++)
        a[i] = *(const bf16x8*)(&As[(wm + i * 16 + m_) * 40 + q * 8]);
#pragma unroll
    for (int j = 0; j < 4; j++)
        b[j] = *(const bf16x8*)(Bbase + (size_t)(j * 16 + m_) * 32 + q * 8);
#pragma unroll
    for (int i = 0; i < 4; i++)
#pragma unroll
        for (int j = 0; j < 4; j++)
            acc[i][j] = __builtin_amdgcn_mfma_f32_16x16x32_bf16(a[i], b[j], acc[i][j], 0, 0, 0);
#pragma unroll
    for (int i = 0; i < 4; i++)
#pragma unroll
        for (int rg = 0; rg < 4; rg++) {
            int grow = m0 + wm + i * 16 + q * 4 + rg;
            if (grow < M) {
#pragma unroll
                for (int j = 0; j < 4; j++) {
                    int gcol = bn * 128 + wn + j * 16 + m_;
                    z[(size_t)grow * 512 + gcol] = f2b(acc[i][j][rg]);
                }
            }
        }
}

// edge2: out[fr][c] += (1/deg[seg]) * z[to, rel*16+c].  16 lanes/edge, already
// line-coalesced (16 consecutive f32 per edge).
__global__ __launch_bounds__(256) void edge2(const int* __restrict__ rel,
                                             const int* __restrict__ fr,
                                             const int* __restrict__ to,
                                             const float* __restrict__ deg,
                                             const unsigned short* __restrict__ z,
                                             float* __restrict__ out) {
    int t = blockIdx.x * 256 + threadIdx.x;
    int e = t >> 4;
    if (e >= E_EDGES) return;
    int c = t & 15;
    int r = rel[e], f = fr[e], u = to[e];
    float v = 1.0f / deg[(size_t)r * N_NODES + f];
    float zz = b2f((unsigned int)z[(size_t)u * 512 + (r << 4) + c]);
    atomicAdd(out + (size_t)f * 16 + c, v * zz);
}

extern "C" void kernel_launch(void* const* d_in, const int* in_sizes, int n_in,
                              void* d_out, int out_size, void* d_ws, size_t ws_size,
                              hipStream_t stream) {
    (void)in_sizes; (void)n_in; (void)out_size; (void)ws_size;
    const float* emb    = (const float*)d_in[0];
    const float* comps1 = (const float*)d_in[1];
    const float* bases1 = (const float*)d_in[2];
    const float* comps2 = (const float*)d_in[3];
    const float* bases2 = (const float*)d_in[4];
    const float* bias1  = (const float*)d_in[5];
    const float* bias2  = (const float*)d_in[6];
    const int* rel = (const int*)d_in[7];
    const int* fr  = (const int*)d_in[8];
    const int* to  = (const int*)d_in[9];
    float* out = (float*)d_out;
    char* ws = (char*)d_ws;

    // workspace layout (all 256B-aligned offsets); total ~237.1 MB
    float* deg            = (float*)(ws);                    // 12.8 MB
    float* hidden1        = (float*)(ws + 12800000);         // 12.8 MB
    unsigned short* h1b   = (unsigned short*)(ws + 25600000);// 6.4 MB
    unsigned short* w1T   = (unsigned short*)(ws + 32000000);// 256 KB
    unsigned short* w2T   = (unsigned short*)(ws + 32262144);// 32 KB
    unsigned short* xw    = (unsigned short*)(ws + 32294912);// 204.8 MB
    unsigned short* z     = xw;  // alias: xw dead after edge1, z written by gemm2

    hipMemsetAsync(deg, 0, 25600000, stream);  // deg + hidden1 (adjacent)
    kw1<<<512, 256, 0, stream>>>(comps1, bases1, w1T);
    kw2<<<64, 256, 0, stream>>>(comps2, bases2, w2T);
    kdeg<<<12500, 256, 0, stream>>>(rel, fr, deg);
    koutinit<<<6250, 256, 0, stream>>>(bias2, out);
    gemm1<<<dim3(8, 782), 256, 0, stream>>>(emb, w1T, xw, N_NODES);
    edge1<<<400000, 256, 0, stream>>>(rel, fr, to, deg, xw, hidden1);
    krelu<<<12500, 256, 0, stream>>>(hidden1, bias1, h1b);
    gemm2<<<dim3(4, 782), 256, 0, stream>>>(h1b, w2T, z, N_NODES);
    edge2<<<200000, 256, 0, stream>>>(rel, fr, to, deg, z, out);
}

// Round 3
// 836.825 us; speedup vs baseline: 4.0033x; 1.2279x over previous
//
#include <hip/hip_runtime.h>

// RGCN embedding, MI355X.  R3: atomic-free edge passes via fr-sorted CSR.
// Pipeline:
//   memset(cnt,cnt2) -> kw1/kw2 (bf16 weights) -> khist(cnt[fr]) -> scan(rowptr)
//   -> kscatter(packed=(rel<<17)|to, fr-grouped) -> GEMM1 xw[N][1024]=emb@w1T
//   -> edge1csr: per-node wave, LDS rel-hist -> vals, gather xw, fused
//      bias1+relu+cast -> h1b  (plain stores, no atomics)
//   -> GEMM2 z[N][512]=h1b@w2T -> edge2csr: gather z, fused bias2 -> out.
#define N_NODES 100000
#define E_EDGES 3200000
#define SCAN_N 100096          // 391 * 256 >= N_NODES+1
#define SCAN_B 391

typedef float f32x4 __attribute__((ext_vector_type(4)));
typedef __bf16 bf16x8 __attribute__((ext_vector_type(8)));

__device__ __forceinline__ float b2f(unsigned int u) {
    union { unsigned int i; float f; } x; x.i = u << 16; return x.f;
}
__device__ __forceinline__ unsigned short f2b(float f) {
    union { float f; unsigned int i; } x; x.f = f;
    unsigned int u = x.i + 0x7FFFu + ((x.i >> 16) & 1u);
    return (unsigned short)(u >> 16);
}

// w1T[j][k] = sum_b comps1[r,b]*bases1[b,k,h], j=r*32+h  (bf16, [1024][128])
__global__ __launch_bounds__(256) void kw1(const float* __restrict__ comps1,
                                           const float* __restrict__ bases1,
                                           unsigned short* __restrict__ w1T) {
    int id = blockIdx.x * 256 + threadIdx.x;
    if (id >= 1024 * 128) return;
    int k = id & 127, j = id >> 7;
    int r = j >> 5, h = j & 31;
    float s = 0.f;
#pragma unroll
    for (int b = 0; b < 16; b++)
        s += comps1[r * 16 + b] * bases1[b * 4096 + k * 32 + h];
    w1T[(size_t)j * 128 + k] = f2b(s);
}

// w2T[j2][h] = sum_b comps2[r,b]*bases2[b,h,c], j2=r*16+c  (bf16, [512][32])
__global__ __launch_bounds__(256) void kw2(const float* __restrict__ comps2,
                                           const float* __restrict__ bases2,
                                           unsigned short* __restrict__ w2T) {
    int id = blockIdx.x * 256 + threadIdx.x;
    if (id >= 512 * 32) return;
    int h = id & 31, j = id >> 5;
    int r = j >> 4, c = j & 15;
    float s = 0.f;
#pragma unroll
    for (int b = 0; b < 16; b++)
        s += comps2[r * 16 + b] * bases2[b * 512 + h * 16 + c];
    w2T[(size_t)j * 32 + h] = f2b(s);
}

__global__ __launch_bounds__(256) void khist(const int* __restrict__ fr,
                                             int* __restrict__ cnt) {
    int e = blockIdx.x * 256 + threadIdx.x;
    if (e >= E_EDGES) return;
    atomicAdd(cnt + fr[e], 1);
}

// block sums of cnt
__global__ __launch_bounds__(256) void ks1(const int* __restrict__ cnt,
                                           int* __restrict__ bsum) {
    __shared__ int sm[256];
    int t = threadIdx.x;
    sm[t] = cnt[blockIdx.x * 256 + t];
    __syncthreads();
    for (int ofs = 128; ofs > 0; ofs >>= 1) {
        if (t < ofs) sm[t] += sm[t + ofs];
        __syncthreads();
    }
    if (t == 0) bsum[blockIdx.x] = sm[0];
}

// exclusive scan of SCAN_B block sums (1 block, 512 thr)
__global__ __launch_bounds__(512) void ks2(const int* __restrict__ bsum,
                                           int* __restrict__ boff) {
    __shared__ int a[512], b[512];
    int t = threadIdx.x;
    int v = (t < SCAN_B) ? bsum[t] : 0;
    a[t] = v;
    __syncthreads();
    int* src = a; int* dst = b;
    for (int ofs = 1; ofs < 512; ofs <<= 1) {
        int x = src[t];
        if (t >= ofs) x += src[t - ofs];
        __syncthreads();
        dst[t] = x;
        __syncthreads();
        int* tmp = src; src = dst; dst = tmp;
    }
    if (t < SCAN_B) boff[t] = src[t] - v;
}

// rowptr[i] = boff[blk] + exclusive-scan-within-block
__global__ __launch_bounds__(256) void ks3(const int* __restrict__ cnt,
                                           const int* __restrict__ boff,
                                           int* __restrict__ rowptr) {
    __shared__ int a[256], b[256];
    int t = threadIdx.x, i = blockIdx.x * 256 + t;
    int v = cnt[i];
    a[t] = v;
    __syncthreads();
    int* src = a; int* dst = b;
    for (int ofs = 1; ofs < 256; ofs <<= 1) {
        int x = src[t];
        if (t >= ofs) x += src[t - ofs];
        __syncthreads();
        dst[t] = x;
        __syncthreads();
        int* tmp = src; src = dst; dst = tmp;
    }
    rowptr[i] = boff[blockIdx.x] + src[t] - v;
}

// scatter edges into fr-grouped order; packed = (rel<<17)|to  (to<2^17, rel<32)
__global__ __launch_bounds__(256) void kscatter(const int* __restrict__ rel,
                                                const int* __restrict__ fr,
                                                const int* __restrict__ to,
                                                const int* __restrict__ rowptr,
                                                int* __restrict__ cnt2,
                                                unsigned int* __restrict__ packed) {
    int e = blockIdx.x * 256 + threadIdx.x;
    if (e >= E_EDGES) return;
    int f = fr[e];
    int pos = rowptr[f] + atomicAdd(cnt2 + f, 1);
    packed[pos] = ((unsigned int)rel[e] << 17) | (unsigned int)to[e];
}

// GEMM1: xw[m][j] = sum_k emb[m][k]*w1T[j][k].  M=100000,N'=1024,K=128.
__global__ __launch_bounds__(256) void gemm1(const float* __restrict__ emb,
                                             const unsigned short* __restrict__ w1T,
                                             unsigned short* __restrict__ xw, int M) {
    __shared__ unsigned short As[128 * 136];
    int tid = threadIdx.x;
    int bn = blockIdx.x;            // 0..7 (8 blocks share an A tile)
    int m0 = blockIdx.y * 128;
#pragma unroll
    for (int i = 0; i < 16; i++) {
        int idx = tid + i * 256;    // 4096 chunks of 4 f32
        int row = idx >> 5, ch = idx & 31;
        int gr = m0 + row;
        float4 v = make_float4(0.f, 0.f, 0.f, 0.f);
        if (gr < M) v = *(const float4*)(emb + (size_t)gr * 128 + ch * 4);
        ushort4 b;
        b.x = f2b(v.x); b.y = f2b(v.y); b.z = f2b(v.z); b.w = f2b(v.w);
        *(ushort4*)(&As[row * 136 + ch * 4]) = b;
    }
    __syncthreads();
    int lane = tid & 63, wave = tid >> 6;
    int wm = (wave & 1) * 64, wn = (wave >> 1) * 64;
    int m_ = lane & 15, q = lane >> 4;
    f32x4 acc[4][4] = {};
    const unsigned short* Bbase = w1T + (size_t)(bn * 128 + wn) * 128;
#pragma unroll
    for (int k0 = 0; k0 < 128; k0 += 32) {
        bf16x8 a[4], b[4];
#pragma unroll
        for (int i = 0; i < 4; i++)
            a[i] = *(const bf16x8*)(&As[(wm + i * 16 + m_) * 136 + k0 + q * 8]);
#pragma unroll
        for (int j = 0; j < 4; j++)
            b[j] = *(const bf16x8*)(Bbase + (size_t)(j * 16 + m_) * 128 + k0 + q * 8);
#pragma unroll
        for (int i = 0; i < 4; i++)
#pragma unroll
            for (int j = 0; j < 4; j++)
                acc[i][j] = __builtin_amdgcn_mfma_f32_16x16x32_bf16(a[i], b[j], acc[i][j], 0, 0, 0);
    }
#pragma unroll
    for (int i = 0; i < 4; i++)
#pragma unroll
        for (int rg = 0; rg < 4; rg++) {
            int grow = m0 + wm + i * 16 + q * 4 + rg;
            if (grow < M) {
#pragma unroll
                for (int j = 0; j < 4; j++) {
                    int gcol = bn * 128 + wn + j * 16 + m_;
                    xw[(size_t)grow * 1024 + gcol] = f2b(acc[i][j][rg]);
                }
            }
        }
}

// edge1csr: one wave per node f.  LDS hist of rels -> vals; gather xw rows
// (2 edges per wave-instr, lane=(p<<5)|h); fused bias1+relu+bf16 store.
__global__ __launch_bounds__(256) void edge1csr(const unsigned int* __restrict__ packed,
                                                const int* __restrict__ rowptr,
                                                const unsigned short* __restrict__ xw,
                                                const float* __restrict__ bias1,
                                                float* __restrict__ vals,
                                                unsigned short* __restrict__ h1b) {
    __shared__ int hist[4 * 32];
    __shared__ unsigned int ebuf[4 * 64];
    __shared__ float vbuf[4 * 64];
    int wave = threadIdx.x >> 6, lane = threadIdx.x & 63;
    int f = blockIdx.x * 4 + wave;
    if (f >= N_NODES) return;
    int s = rowptr[f], k = rowptr[f + 1] - s;
    if (lane < 32) hist[wave * 32 + lane] = 0;
    for (int base = 0; base < k; base += 64) {
        int e = base + lane;
        if (e < k) atomicAdd(&hist[wave * 32 + (packed[s + e] >> 17)], 1);
    }
    int p = lane >> 5, h = lane & 31;
    float acc = 0.f;
    for (int base = 0; base < k; base += 64) {
        int e = base + lane;
        if (e < k) {
            unsigned int pk = packed[s + e];
            float v = 1.0f / (float)hist[wave * 32 + (pk >> 17)];
            vals[s + e] = v;
            ebuf[wave * 64 + lane] = pk;
            vbuf[wave * 64 + lane] = v;
        }
        int cnum = min(64, k - base);
        int nst = (cnum + 1) >> 1;
#pragma unroll 4
        for (int i = 0; i < nst; i++) {
            int ei = 2 * i + p;
            if (ei < cnum) {
                unsigned int pk = ebuf[wave * 64 + ei];
                float v = vbuf[wave * 64 + ei];
                int t_ = pk & 0x1FFFF, r = pk >> 17;
                acc += v * b2f((unsigned int)xw[(size_t)t_ * 1024 + (r << 5) + h]);
            }
        }
    }
    acc += __shfl_xor(acc, 32, 64);
    if (p == 0) {
        float x = acc + bias1[h];
        h1b[(size_t)f * 32 + h] = f2b(fmaxf(x, 0.f));
    }
}

// GEMM2: z[m][j2] = sum_h h1b[m][h]*w2T[j2][h].  M=100000,N'=512,K=32.
__global__ __launch_bounds__(256) void gemm2(const unsigned short* __restrict__ h1b,
                                             const unsigned short* __restrict__ w2T,
                                             unsigned short* __restrict__ z, int M) {
    __shared__ unsigned short As[128 * 40];
    int tid = threadIdx.x;
    int bn = blockIdx.x;            // 0..3
    int m0 = blockIdx.y * 128;
#pragma unroll
    for (int i = 0; i < 2; i++) {
        int idx = tid + i * 256;
        int row = idx >> 2, ch = idx & 3;
        int gr = m0 + row;
        uint4 v = make_uint4(0u, 0u, 0u, 0u);
        if (gr < M) v = *(const uint4*)(h1b + (size_t)gr * 32 + ch * 8);
        *(uint4*)(&As[row * 40 + ch * 8]) = v;
    }
    __syncthreads();
    int lane = tid & 63, wave = tid >> 6;
    int wm = (wave & 1) * 64, wn = (wave >> 1) * 64;
    int m_ = lane & 15, q = lane >> 4;
    f32x4 acc[4][4] = {};
    const unsigned short* Bbase = w2T + (size_t)(bn * 128 + wn) * 32;
    bf16x8 a[4], b[4];
#pragma unroll
    for (int i = 0; i < 4; i++)
        a[i] = *(const bf16x8*)(&As[(wm + i * 16 + m_) * 40 + q * 8]);
#pragma unroll
    for (int j = 0; j < 4; j++)
        b[j] = *(const bf16x8*)(Bbase + (size_t)(j * 16 + m_) * 32 + q * 8);
#pragma unroll
    for (int i = 0; i < 4; i++)
#pragma unroll
        for (int j = 0; j < 4; j++)
            acc[i][j] = __builtin_amdgcn_mfma_f32_16x16x32_bf16(a[i], b[j], acc[i][j], 0, 0, 0);
#pragma unroll
    for (int i = 0; i < 4; i++)
#pragma unroll
        for (int rg = 0; rg < 4; rg++) {
            int grow = m0 + wm + i * 16 + q * 4 + rg;
            if (grow < M) {
#pragma unroll
                for (int j = 0; j < 4; j++) {
                    int gcol = bn * 128 + wn + j * 16 + m_;
                    z[(size_t)grow * 512 + gcol] = f2b(acc[i][j][rg]);
                }
            }
        }
}

// edge2csr: one wave per node.  Gather z rows (4 edges/instr, lane=(q<<4)|c),
// reduce via shfl, fused bias2, plain store of out row.
__global__ __launch_bounds__(256) void edge2csr(const unsigned int* __restrict__ packed,
                                                const int* __restrict__ rowptr,
                                                const float* __restrict__ vals,
                                                const unsigned short* __restrict__ z,
                                                const float* __restrict__ bias2,
                                                float* __restrict__ out) {
    __shared__ unsigned int ebuf[4 * 64];
    __shared__ float vbuf[4 * 64];
    int wave = threadIdx.x >> 6, lane = threadIdx.x & 63;
    int f = blockIdx.x * 4 + wave;
    if (f >= N_NODES) return;
    int s = rowptr[f], k = rowptr[f + 1] - s;
    int q = lane >> 4, c = lane & 15;
    float acc = 0.f;
    for (int base = 0; base < k; base += 64) {
        int e = base + lane;
        if (e < k) {
            ebuf[wave * 64 + lane] = packed[s + e];
            vbuf[wave * 64 + lane] = vals[s + e];
        }
        int cnum = min(64, k - base);
        int nst = (cnum + 3) >> 2;
#pragma unroll 4
        for (int i = 0; i < nst; i++) {
            int ei = 4 * i + q;
            if (ei < cnum) {
                unsigned int pk = ebuf[wave * 64 + ei];
                float v = vbuf[wave * 64 + ei];
                int t_ = pk & 0x1FFFF, r = pk >> 17;
                acc += v * b2f((unsigned int)z[(size_t)t_ * 512 + (r << 4) + c]);
            }
        }
    }
    acc += __shfl_xor(acc, 32, 64);
    acc += __shfl_xor(acc, 16, 64);
    if (q == 0) out[(size_t)f * 16 + c] = bias2[c] + acc;
}

extern "C" void kernel_launch(void* const* d_in, const int* in_sizes, int n_in,
                              void* d_out, int out_size, void* d_ws, size_t ws_size,
                              hipStream_t stream) {
    (void)in_sizes; (void)n_in; (void)out_size; (void)ws_size;
    const float* emb    = (const float*)d_in[0];
    const float* comps1 = (const float*)d_in[1];
    const float* bases1 = (const float*)d_in[2];
    const float* comps2 = (const float*)d_in[3];
    const float* bases2 = (const float*)d_in[4];
    const float* bias1  = (const float*)d_in[5];
    const float* bias2  = (const float*)d_in[6];
    const int* rel = (const int*)d_in[7];
    const int* fr  = (const int*)d_in[8];
    const int* to  = (const int*)d_in[9];
    float* out = (float*)d_out;
    char* ws = (char*)d_ws;

    // workspace layout (offsets in bytes, 256-aligned); total ~238.3 MB
    int* cnt             = (int*)(ws);                        // 400,384 B
    int* cnt2            = (int*)(ws + 400384);               // 400,384 B
    int* rowptr          = (int*)(ws + 800768);               // 400,388 B
    int* bsum            = (int*)(ws + 1201408);              // 391*4
    int* boff            = (int*)(ws + 1203456);              // 391*4
    unsigned int* packed = (unsigned int*)(ws + 1205504);     // 12.8 MB
    float* vals          = (float*)(ws + 14005504);           // 12.8 MB
    unsigned short* h1b  = (unsigned short*)(ws + 26805504);  // 6.4 MB
    unsigned short* w1T  = (unsigned short*)(ws + 33205504);  // 256 KB
    unsigned short* w2T  = (unsigned short*)(ws + 33467648);  // 32 KB
    unsigned short* xw   = (unsigned short*)(ws + 33500416);  // 204.8 MB
    unsigned short* z    = xw;  // alias: xw dead before gemm2 writes z

    hipMemsetAsync(cnt, 0, 800768, stream);   // cnt + cnt2 (adjacent)
    kw1<<<512, 256, 0, stream>>>(comps1, bases1, w1T);
    kw2<<<64, 256, 0, stream>>>(comps2, bases2, w2T);
    khist<<<12500, 256, 0, stream>>>(fr, cnt);
    ks1<<<SCAN_B, 256, 0, stream>>>(cnt, bsum);
    ks2<<<1, 512, 0, stream>>>(bsum, boff);
    ks3<<<SCAN_B, 256, 0, stream>>>(cnt, boff, rowptr);
    kscatter<<<12500, 256, 0, stream>>>(rel, fr, to, rowptr, cnt2, packed);
    gemm1<<<dim3(8, 782), 256, 0, stream>>>(emb, w1T, xw, N_NODES);
    edge1csr<<<25000, 256, 0, stream>>>(packed, rowptr, xw, bias1, vals, h1b);
    gemm2<<<dim3(4, 782), 256, 0, stream>>>(h1b, w2T, z, N_NODES);
    edge2csr<<<25000, 256, 0, stream>>>(packed, rowptr, vals, z, bias2, out);
}

// Round 4
// 788.707 us; speedup vs baseline: 4.2476x; 1.0610x over previous
//
#include <hip/hip_runtime.h>

// RGCN embedding, MI355X.  R4: LDS-free GEMMs with operand-swapped MFMA
// (ushort4 stores), emb pre-cast to bf16, vals array dropped (edge2 recomputes
// the per-node rel histogram).  Edge passes stay atomic-free via fr-CSR.
#define N_NODES 100000
#define N_PAD   100096         // 782*128 rows covered by GEMM grids
#define E_EDGES 3200000
#define SCAN_N  100096         // 391*256 >= N_NODES+1
#define SCAN_B  391

typedef float f32x4 __attribute__((ext_vector_type(4)));
typedef __bf16 bf16x8 __attribute__((ext_vector_type(8)));

__device__ __forceinline__ float b2f(unsigned int u) {
    union { unsigned int i; float f; } x; x.i = u << 16; return x.f;
}
__device__ __forceinline__ unsigned short f2b(float f) {
    union { float f; unsigned int i; } x; x.f = f;
    unsigned int u = x.i + 0x7FFFu + ((x.i >> 16) & 1u);
    return (unsigned short)(u >> 16);
}

// emb f32 -> bf16, padded to N_PAD rows (pad = 0)
__global__ __launch_bounds__(256) void kemb(const float* __restrict__ emb,
                                            unsigned short* __restrict__ embb) {
    int id = blockIdx.x * 256 + threadIdx.x;     // 8 elements per thread
    if (id >= N_PAD * 128 / 8) return;
    size_t base = (size_t)id * 8;
    ushort4 o0 = {0, 0, 0, 0}, o1 = {0, 0, 0, 0};
    if (base < (size_t)N_NODES * 128) {
        float4 v0 = *(const float4*)(emb + base);
        float4 v1 = *(const float4*)(emb + base + 4);
        o0.x = f2b(v0.x); o0.y = f2b(v0.y); o0.z = f2b(v0.z); o0.w = f2b(v0.w);
        o1.x = f2b(v1.x); o1.y = f2b(v1.y); o1.z = f2b(v1.z); o1.w = f2b(v1.w);
    }
    *(ushort4*)(embb + base) = o0;
    *(ushort4*)(embb + base + 4) = o1;
}

// w1T[j][k] = sum_b comps1[r,b]*bases1[b,k,h], j=r*32+h  (bf16, [1024][128])
__global__ __launch_bounds__(256) void kw1(const float* __restrict__ comps1,
                                           const float* __restrict__ bases1,
                                           unsigned short* __restrict__ w1T) {
    int id = blockIdx.x * 256 + threadIdx.x;
    if (id >= 1024 * 128) return;
    int k = id & 127, j = id >> 7;
    int r = j >> 5, h = j & 31;
    float s = 0.f;
#pragma unroll
    for (int b = 0; b < 16; b++)
        s += comps1[r * 16 + b] * bases1[b * 4096 + k * 32 + h];
    w1T[(size_t)j * 128 + k] = f2b(s);
}

// w2T[j2][h] = sum_b comps2[r,b]*bases2[b,h,c], j2=r*16+c  (bf16, [512][32])
__global__ __launch_bounds__(256) void kw2(const float* __restrict__ comps2,
                                           const float* __restrict__ bases2,
                                           unsigned short* __restrict__ w2T) {
    int id = blockIdx.x * 256 + threadIdx.x;
    if (id >= 512 * 32) return;
    int h = id & 31, j = id >> 5;
    int r = j >> 4, c = j & 15;
    float s = 0.f;
#pragma unroll
    for (int b = 0; b < 16; b++)
        s += comps2[r * 16 + b] * bases2[b * 512 + h * 16 + c];
    w2T[(size_t)j * 32 + h] = f2b(s);
}

__global__ __launch_bounds__(256) void khist(const int* __restrict__ fr,
                                             int* __restrict__ cnt) {
    int e = blockIdx.x * 256 + threadIdx.x;
    if (e >= E_EDGES) return;
    atomicAdd(cnt + fr[e], 1);
}

__global__ __launch_bounds__(256) void ks1(const int* __restrict__ cnt,
                                           int* __restrict__ bsum) {
    __shared__ int sm[256];
    int t = threadIdx.x;
    sm[t] = cnt[blockIdx.x * 256 + t];
    __syncthreads();
    for (int ofs = 128; ofs > 0; ofs >>= 1) {
        if (t < ofs) sm[t] += sm[t + ofs];
        __syncthreads();
    }
    if (t == 0) bsum[blockIdx.x] = sm[0];
}

__global__ __launch_bounds__(512) void ks2(const int* __restrict__ bsum,
                                           int* __restrict__ boff) {
    __shared__ int a[512], b[512];
    int t = threadIdx.x;
    int v = (t < SCAN_B) ? bsum[t] : 0;
    a[t] = v;
    __syncthreads();
    int* src = a; int* dst = b;
    for (int ofs = 1; ofs < 512; ofs <<= 1) {
        int x = src[t];
        if (t >= ofs) x += src[t - ofs];
        __syncthreads();
        dst[t] = x;
        __syncthreads();
        int* tmp = src; src = dst; dst = tmp;
    }
    if (t < SCAN_B) boff[t] = src[t] - v;
}

__global__ __launch_bounds__(256) void ks3(const int* __restrict__ cnt,
                                           const int* __restrict__ boff,
                                           int* __restrict__ rowptr) {
    __shared__ int a[256], b[256];
    int t = threadIdx.x, i = blockIdx.x * 256 + t;
    int v = cnt[i];
    a[t] = v;
    __syncthreads();
    int* src = a; int* dst = b;
    for (int ofs = 1; ofs < 256; ofs <<= 1) {
        int x = src[t];
        if (t >= ofs) x += src[t - ofs];
        __syncthreads();
        dst[t] = x;
        __syncthreads();
        int* tmp = src; src = dst; dst = tmp;
    }
    rowptr[i] = boff[blockIdx.x] + src[t] - v;
}

// packed = (rel<<17)|to, fr-grouped
__global__ __launch_bounds__(256) void kscatter(const int* __restrict__ rel,
                                                const int* __restrict__ fr,
                                                const int* __restrict__ to,
                                                const int* __restrict__ rowptr,
                                                int* __restrict__ cnt2,
                                                unsigned int* __restrict__ packed) {
    int e = blockIdx.x * 256 + threadIdx.x;
    if (e >= E_EDGES) return;
    int f = fr[e];
    int pos = rowptr[f] + atomicAdd(cnt2 + f, 1);
    packed[pos] = ((unsigned int)rel[e] << 17) | (unsigned int)to[e];
}

// GEMM1 (LDS-free): xw[m][j] = sum_k embb[m][k]*w1T[j][k].  M rows, N'=1024, K=128.
// Wave tile 64m x 64n; operands swapped -> D[n][m]: lane m_=out col (node row),
// regs = 4 consecutive n -> ushort4 stores.
__global__ __launch_bounds__(256) void gemm1(const unsigned short* __restrict__ embb,
                                             const unsigned short* __restrict__ w1T,
                                             unsigned short* __restrict__ xw, int M) {
    int tid = threadIdx.x;
    int bn = blockIdx.x;            // 0..7
    int m0 = blockIdx.y * 128;
    int lane = tid & 63, wave = tid >> 6;
    int wm = (wave & 1) * 64, wn = (wave >> 1) * 64;
    int m_ = lane & 15, q = lane >> 4;
    f32x4 acc[4][4] = {};
    const unsigned short* Abase = embb + (size_t)(m0 + wm + m_) * 128 + q * 8;
    const unsigned short* Bbase = w1T + (size_t)(bn * 128 + wn + m_) * 128 + q * 8;
#pragma unroll
    for (int k0 = 0; k0 < 128; k0 += 32) {
        bf16x8 a[4], b[4];
#pragma unroll
        for (int i = 0; i < 4; i++)
            a[i] = *(const bf16x8*)(Abase + (size_t)i * 16 * 128 + k0);
#pragma unroll
        for (int j = 0; j < 4; j++)
            b[j] = *(const bf16x8*)(Bbase + (size_t)j * 16 * 128 + k0);
#pragma unroll
        for (int i = 0; i < 4; i++)
#pragma unroll
            for (int j = 0; j < 4; j++)
                acc[i][j] = __builtin_amdgcn_mfma_f32_16x16x32_bf16(b[j], a[i], acc[i][j], 0, 0, 0);
    }
#pragma unroll
    for (int i = 0; i < 4; i++) {
        int grow = m0 + wm + i * 16 + m_;
        if (grow < M) {
#pragma unroll
            for (int j = 0; j < 4; j++) {
                int gcol = bn * 128 + wn + j * 16 + q * 4;
                ushort4 s;
                s.x = f2b(acc[i][j][0]); s.y = f2b(acc[i][j][1]);
                s.z = f2b(acc[i][j][2]); s.w = f2b(acc[i][j][3]);
                *(ushort4*)(xw + (size_t)grow * 1024 + gcol) = s;
            }
        }
    }
}

// edge1csr: one wave per node f.  LDS rel-hist -> vals; gather xw rows
// (2 edges per wave-instr, lane=(p<<5)|h); fused bias1+relu+bf16 store.
__global__ __launch_bounds__(256) void edge1csr(const unsigned int* __restrict__ packed,
                                                const int* __restrict__ rowptr,
                                                const unsigned short* __restrict__ xw,
                                                const float* __restrict__ bias1,
                                                unsigned short* __restrict__ h1b) {
    __shared__ int hist[4 * 32];
    __shared__ unsigned int ebuf[4 * 64];
    __shared__ float vbuf[4 * 64];
    int wave = threadIdx.x >> 6, lane = threadIdx.x & 63;
    int f = blockIdx.x * 4 + wave;
    if (f >= N_NODES) return;
    int s = rowptr[f], k = rowptr[f + 1] - s;
    if (lane < 32) hist[wave * 32 + lane] = 0;
    for (int base = 0; base < k; base += 64) {
        int e = base + lane;
        if (e < k) atomicAdd(&hist[wave * 32 + (packed[s + e] >> 17)], 1);
    }
    int p = lane >> 5, h = lane & 31;
    float acc = 0.f;
    for (int base = 0; base < k; base += 64) {
        int e = base + lane;
        if (e < k) {
            unsigned int pk = packed[s + e];
            ebuf[wave * 64 + lane] = pk;
            vbuf[wave * 64 + lane] = 1.0f / (float)hist[wave * 32 + (pk >> 17)];
        }
        int cnum = min(64, k - base);
        int nst = (cnum + 1) >> 1;
#pragma unroll 4
        for (int i = 0; i < nst; i++) {
            int ei = 2 * i + p;
            if (ei < cnum) {
                unsigned int pk = ebuf[wave * 64 + ei];
                float v = vbuf[wave * 64 + ei];
                int t_ = pk & 0x1FFFF, r = pk >> 17;
                acc += v * b2f((unsigned int)xw[(size_t)t_ * 1024 + (r << 5) + h]);
            }
        }
    }
    acc += __shfl_xor(acc, 32, 64);
    if (p == 0) {
        float x = acc + bias1[h];
        h1b[(size_t)f * 32 + h] = f2b(fmaxf(x, 0.f));
    }
}

// GEMM2 (LDS-free): z[m][j2] = sum_h h1b[m][h]*w2T[j2][h].  K=32 (one MFMA step).
__global__ __launch_bounds__(256) void gemm2(const unsigned short* __restrict__ h1b,
                                             const unsigned short* __restrict__ w2T,
                                             unsigned short* __restrict__ z, int M) {
    int tid = threadIdx.x;
    int bn = blockIdx.x;            // 0..3
    int m0 = blockIdx.y * 128;
    int lane = tid & 63, wave = tid >> 6;
    int wm = (wave & 1) * 64, wn = (wave >> 1) * 64;
    int m_ = lane & 15, q = lane >> 4;
    f32x4 acc[4][4] = {};
    const unsigned short* Abase = h1b + (size_t)(m0 + wm + m_) * 32 + q * 8;
    const unsigned short* Bbase = w2T + (size_t)(bn * 128 + wn + m_) * 32 + q * 8;
    bf16x8 a[4], b[4];
#pragma unroll
    for (int i = 0; i < 4; i++)
        a[i] = *(const bf16x8*)(Abase + (size_t)i * 16 * 32);
#pragma unroll
    for (int j = 0; j < 4; j++)
        b[j] = *(const bf16x8*)(Bbase + (size_t)j * 16 * 32);
#pragma unroll
    for (int i = 0; i < 4; i++)
#pragma unroll
        for (int j = 0; j < 4; j++)
            acc[i][j] = __builtin_amdgcn_mfma_f32_16x16x32_bf16(b[j], a[i], acc[i][j], 0, 0, 0);
#pragma unroll
    for (int i = 0; i < 4; i++) {
        int grow = m0 + wm + i * 16 + m_;
        if (grow < M) {
#pragma unroll
            for (int j = 0; j < 4; j++) {
                int gcol = bn * 128 + wn + j * 16 + q * 4;
                ushort4 s;
                s.x = f2b(acc[i][j][0]); s.y = f2b(acc[i][j][1]);
                s.z = f2b(acc[i][j][2]); s.w = f2b(acc[i][j][3]);
                *(ushort4*)(z + (size_t)grow * 512 + gcol) = s;
            }
        }
    }
}

// edge2csr: one wave per node; recompute rel-hist (vals), gather z (4 edges/instr),
// shfl-reduce, fused bias2, plain 64B store.
__global__ __launch_bounds__(256) void edge2csr(const unsigned int* __restrict__ packed,
                                                const int* __restrict__ rowptr,
                                                const unsigned short* __restrict__ z,
                                                const float* __restrict__ bias2,
                                                float* __restrict__ out) {
    __shared__ int hist[4 * 32];
    __shared__ unsigned int ebuf[4 * 64];
    __shared__ float vbuf[4 * 64];
    int wave = threadIdx.x >> 6, lane = threadIdx.x & 63;
    int f = blockIdx.x * 4 + wave;
    if (f >= N_NODES) return;
    int s = rowptr[f], k = rowptr[f + 1] - s;
    if (lane < 32) hist[wave * 32 + lane] = 0;
    for (int base = 0; base < k; base += 64) {
        int e = base + lane;
        if (e < k) atomicAdd(&hist[wave * 32 + (packed[s + e] >> 17)], 1);
    }
    int q = lane >> 4, c = lane & 15;
    float acc = 0.f;
    for (int base = 0; base < k; base += 64) {
        int e = base + lane;
        if (e < k) {
            unsigned int pk = packed[s + e];
            ebuf[wave * 64 + lane] = pk;
            vbuf[wave * 64 + lane] = 1.0f / (float)hist[wave * 32 + (pk >> 17)];
        }
        int cnum = min(64, k - base);
        int nst = (cnum + 3) >> 2;
#pragma unroll 4
        for (int i = 0; i < nst; i++) {
            int ei = 4 * i + q;
            if (ei < cnum) {
                unsigned int pk = ebuf[wave * 64 + ei];
                float v = vbuf[wave * 64 + ei];
                int t_ = pk & 0x1FFFF, r = pk >> 17;
                acc += v * b2f((unsigned int)z[(size_t)t_ * 512 + (r << 4) + c]);
            }
        }
    }
    acc += __shfl_xor(acc, 32, 64);
    acc += __shfl_xor(acc, 16, 64);
    if (q == 0) out[(size_t)f * 16 + c] = bias2[c] + acc;
}

extern "C" void kernel_launch(void* const* d_in, const int* in_sizes, int n_in,
                              void* d_out, int out_size, void* d_ws, size_t ws_size,
                              hipStream_t stream) {
    (void)in_sizes; (void)n_in; (void)out_size; (void)ws_size;
    const float* emb    = (const float*)d_in[0];
    const float* comps1 = (const float*)d_in[1];
    const float* bases1 = (const float*)d_in[2];
    const float* comps2 = (const float*)d_in[3];
    const float* bases2 = (const float*)d_in[4];
    const float* bias1  = (const float*)d_in[5];
    const float* bias2  = (const float*)d_in[6];
    const int* rel = (const int*)d_in[7];
    const int* fr  = (const int*)d_in[8];
    const int* to  = (const int*)d_in[9];
    float* out = (float*)d_out;
    char* ws = (char*)d_ws;

    // workspace layout (bytes); total ~251.1 MB
    int* cnt             = (int*)(ws);                        // 400,384
    int* cnt2            = (int*)(ws + 400384);               // 400,384
    int* rowptr          = (int*)(ws + 800768);               // 400,388
    int* bsum            = (int*)(ws + 1201408);              // 1,564
    int* boff            = (int*)(ws + 1203456);              // 1,564
    unsigned int* packed = (unsigned int*)(ws + 1205504);     // 12.8 MB
    unsigned short* h1b  = (unsigned short*)(ws + 14005504);  // 6,406,144 (N_PAD x 32)
    unsigned short* w1T  = (unsigned short*)(ws + 20411648);  // 262,144
    unsigned short* w2T  = (unsigned short*)(ws + 20673792);  // 32,768
    unsigned short* embb = (unsigned short*)(ws + 20706560);  // 25,624,576 (N_PAD x 128)
    unsigned short* xw   = (unsigned short*)(ws + 46331136);  // 204,800,000
    unsigned short* z    = xw;  // alias: xw dead before gemm2 writes z

    hipMemsetAsync(cnt, 0, 800768, stream);   // cnt + cnt2 (adjacent)
    kemb<<<6256, 256, 0, stream>>>(emb, embb);
    kw1<<<512, 256, 0, stream>>>(comps1, bases1, w1T);
    kw2<<<64, 256, 0, stream>>>(comps2, bases2, w2T);
    khist<<<12500, 256, 0, stream>>>(fr, cnt);
    ks1<<<SCAN_B, 256, 0, stream>>>(cnt, bsum);
    ks2<<<1, 512, 0, stream>>>(bsum, boff);
    ks3<<<SCAN_B, 256, 0, stream>>>(cnt, boff, rowptr);
    kscatter<<<12500, 256, 0, stream>>>(rel, fr, to, rowptr, cnt2, packed);
    gemm1<<<dim3(8, 782), 256, 0, stream>>>(embb, w1T, xw, N_NODES);
    edge1csr<<<25000, 256, 0, stream>>>(packed, rowptr, xw, bias1, h1b);
    gemm2<<<dim3(4, 782), 256, 0, stream>>>(h1b, w2T, z, N_NODES);
    edge2csr<<<25000, 256, 0, stream>>>(packed, rowptr, z, bias2, out);
}

// Round 5
// 554.296 us; speedup vs baseline: 6.0439x; 1.4229x over previous
//
#include <hip/hip_runtime.h>

// RGCN embedding, MI355X.  R5: bucketed CSR build (no global line-grain
// atomics/scatter), LDS-free MFMA GEMMs, wide-gather edge passes.
// Pipeline:
//   kcur -> kemb/kw1/kw2 -> kbinA (bin edges by fr>>8 into stage, cursor-claimed)
//   -> kscan (bucket bases) -> kscatter2 (per-bucket LDS hist/scan -> rowptr+packed)
//   -> gemm1 xw=embb@w1T -> edge1csr (gather xw, fused bias+relu) -> gemm2 z=h1b@w2T
//   -> edge2csr (gather z, fused bias2) -> out.
#define N_NODES 100000
#define N_PAD   100096         // 782*128 rows covered by GEMM grids
#define E_EDGES 3200000
#define NB      392            // buckets of 256 nodes: 392*256 = 100352 >= N+1
#define BCAP    12288          // mean 8192, sd ~90 -> +45 sd, cannot overflow
#define EPB     16384          // edges per kbinA block

typedef float f32x4 __attribute__((ext_vector_type(4)));
typedef __bf16 bf16x8 __attribute__((ext_vector_type(8)));

__device__ __forceinline__ float b2f(unsigned int u) {
    union { unsigned int i; float f; } x; x.i = u << 16; return x.f;
}
__device__ __forceinline__ unsigned short f2b(float f) {
    union { float f; unsigned int i; } x; x.f = f;
    unsigned int u = x.i + 0x7FFFu + ((x.i >> 16) & 1u);
    return (unsigned short)(u >> 16);
}

__global__ __launch_bounds__(256) void kcur(int* __restrict__ gCursor) {
    int id = blockIdx.x * 256 + threadIdx.x;
    if (id < NB) gCursor[id] = id * BCAP;
}

// emb f32 -> bf16, padded to N_PAD rows (pad = 0)
__global__ __launch_bounds__(256) void kemb(const float* __restrict__ emb,
                                            unsigned short* __restrict__ embb) {
    int id = blockIdx.x * 256 + threadIdx.x;     // 8 elements per thread
    if (id >= N_PAD * 128 / 8) return;
    size_t base = (size_t)id * 8;
    ushort4 o0 = {0, 0, 0, 0}, o1 = {0, 0, 0, 0};
    if (base < (size_t)N_NODES * 128) {
        float4 v0 = *(const float4*)(emb + base);
        float4 v1 = *(const float4*)(emb + base + 4);
        o0.x = f2b(v0.x); o0.y = f2b(v0.y); o0.z = f2b(v0.z); o0.w = f2b(v0.w);
        o1.x = f2b(v1.x); o1.y = f2b(v1.y); o1.z = f2b(v1.z); o1.w = f2b(v1.w);
    }
    *(ushort4*)(embb + base) = o0;
    *(ushort4*)(embb + base + 4) = o1;
}

// w1T[j][k] = sum_b comps1[r,b]*bases1[b,k,h], j=r*32+h  (bf16, [1024][128])
__global__ __launch_bounds__(256) void kw1(const float* __restrict__ comps1,
                                           const float* __restrict__ bases1,
                                           unsigned short* __restrict__ w1T) {
    int id = blockIdx.x * 256 + threadIdx.x;
    if (id >= 1024 * 128) return;
    int k = id & 127, j = id >> 7;
    int r = j >> 5, h = j & 31;
    float s = 0.f;
#pragma unroll
    for (int b = 0; b < 16; b++)
        s += comps1[r * 16 + b] * bases1[b * 4096 + k * 32 + h];
    w1T[(size_t)j * 128 + k] = f2b(s);
}

// w2T[j2][h] = sum_b comps2[r,b]*bases2[b,h,c], j2=r*16+c  (bf16, [512][32])
__global__ __launch_bounds__(256) void kw2(const float* __restrict__ comps2,
                                           const float* __restrict__ bases2,
                                           unsigned short* __restrict__ w2T) {
    int id = blockIdx.x * 256 + threadIdx.x;
    if (id >= 512 * 32) return;
    int h = id & 31, j = id >> 5;
    int r = j >> 4, c = j & 15;
    float s = 0.f;
#pragma unroll
    for (int b = 0; b < 16; b++)
        s += comps2[r * 16 + b] * bases2[b * 512 + h * 16 + c];
    w2T[(size_t)j * 32 + h] = f2b(s);
}

// Bin edges into per-bucket stage regions.  stage word = (frlo<<22)|(rel<<17)|to.
// Cursor claims are one atomicAdd per (block,bucket) with lane-consecutive
// addresses -> coalesced; stage writes are per-block contiguous runs.
__global__ __launch_bounds__(256) void kbinA(const int* __restrict__ rel,
                                             const int* __restrict__ fr,
                                             const int* __restrict__ to,
                                             int* __restrict__ gCursor,
                                             unsigned int* __restrict__ stage) {
    __shared__ int cnt[NB];
    __shared__ int base[NB];
    int tid = threadIdx.x;
    int e0 = blockIdx.x * EPB;
    for (int i = tid; i < NB; i += 256) cnt[i] = 0;
    __syncthreads();
#pragma unroll 4
    for (int i = 0; i < EPB / 256; i++) {
        int e = e0 + i * 256 + tid;
        if (e < E_EDGES) atomicAdd(&cnt[fr[e] >> 8], 1);
    }
    __syncthreads();
    for (int i = tid; i < NB; i += 256) {
        base[i] = atomicAdd(&gCursor[i], cnt[i]);
        cnt[i] = 0;
    }
    __syncthreads();
#pragma unroll 4
    for (int i = 0; i < EPB / 256; i++) {
        int e = e0 + i * 256 + tid;
        if (e < E_EDGES) {
            int f = fr[e];
            int b = f >> 8;
            int rank = atomicAdd(&cnt[b], 1);
            stage[base[b] + rank] =
                ((unsigned int)(f & 255) << 22) | ((unsigned int)rel[e] << 17) | (unsigned int)to[e];
        }
    }
}

// exclusive scan of bucket counts (from cursors) -> bucketBase
__global__ __launch_bounds__(512) void kscan(const int* __restrict__ gCursor,
                                             int* __restrict__ bucketBase) {
    __shared__ int a[512], b[512];
    int t = threadIdx.x;
    int v = (t < NB) ? (gCursor[t] - t * BCAP) : 0;
    a[t] = v;
    __syncthreads();
    int* src = a; int* dst = b;
    for (int ofs = 1; ofs < 512; ofs <<= 1) {
        int x = src[t];
        if (t >= ofs) x += src[t - ofs];
        __syncthreads();
        dst[t] = x;
        __syncthreads();
        int* tmp = src; src = dst; dst = tmp;
    }
    if (t < NB) bucketBase[t] = src[t] - v;
}

// Per-bucket: LDS hist over 256 nodes -> exclusive scan -> rowptr (coalesced),
// then scatter packed within the bucket's L2-resident window.  Zero global atomics.
__global__ __launch_bounds__(256) void kscatter2(const unsigned int* __restrict__ stage,
                                                 const int* __restrict__ gCursor,
                                                 const int* __restrict__ bucketBase,
                                                 int* __restrict__ rowptr,
                                                 unsigned int* __restrict__ packed) {
    __shared__ int hist[256], hexcl[256], rk[256], sa[256], sb[256];
    int b = blockIdx.x, t = threadIdx.x;
    int nb = gCursor[b] - b * BCAP;
    int sbase = b * BCAP;
    int gbase = bucketBase[b];
    hist[t] = 0; rk[t] = 0;
    __syncthreads();
    for (int i = t; i < nb; i += 256)
        atomicAdd(&hist[stage[sbase + i] >> 22], 1);
    __syncthreads();
    int v = hist[t];
    sa[t] = v;
    __syncthreads();
    int* src = sa; int* dst = sb;
    for (int ofs = 1; ofs < 256; ofs <<= 1) {
        int x = src[t];
        if (t >= ofs) x += src[t - ofs];
        __syncthreads();
        dst[t] = x;
        __syncthreads();
        int* tmp = src; src = dst; dst = tmp;
    }
    int excl = src[t] - v;
    hexcl[t] = excl;
    rowptr[b * 256 + t] = gbase + excl;
    __syncthreads();
    for (int i = t; i < nb; i += 256) {
        unsigned int pk = stage[sbase + i];
        int frlo = pk >> 22;
        int rank = atomicAdd(&rk[frlo], 1);
        packed[gbase + hexcl[frlo] + rank] = pk & 0x3FFFFFu;
    }
}

// GEMM1 (LDS-free): xw[m][j] = sum_k embb[m][k]*w1T[j][k].  M rows, N'=1024, K=128.
// Operands swapped -> D[n][m]: lane m_=node row, regs = 4 consecutive cols -> ushort4.
__global__ __launch_bounds__(256) void gemm1(const unsigned short* __restrict__ embb,
                                             const unsigned short* __restrict__ w1T,
                                             unsigned short* __restrict__ xw, int M) {
    int tid = threadIdx.x;
    int bn = blockIdx.x;            // 0..7
    int m0 = blockIdx.y * 128;
    int lane = tid & 63, wave = tid >> 6;
    int wm = (wave & 1) * 64, wn = (wave >> 1) * 64;
    int m_ = lane & 15, q = lane >> 4;
    f32x4 acc[4][4] = {};
    const unsigned short* Abase = embb + (size_t)(m0 + wm + m_) * 128 + q * 8;
    const unsigned short* Bbase = w1T + (size_t)(bn * 128 + wn + m_) * 128 + q * 8;
#pragma unroll
    for (int k0 = 0; k0 < 128; k0 += 32) {
        bf16x8 a[4], b[4];
#pragma unroll
        for (int i = 0; i < 4; i++)
            a[i] = *(const bf16x8*)(Abase + (size_t)i * 16 * 128 + k0);
#pragma unroll
        for (int j = 0; j < 4; j++)
            b[j] = *(const bf16x8*)(Bbase + (size_t)j * 16 * 128 + k0);
#pragma unroll
        for (int i = 0; i < 4; i++)
#pragma unroll
            for (int j = 0; j < 4; j++)
                acc[i][j] = __builtin_amdgcn_mfma_f32_16x16x32_bf16(b[j], a[i], acc[i][j], 0, 0, 0);
    }
#pragma unroll
    for (int i = 0; i < 4; i++) {
        int grow = m0 + wm + i * 16 + m_;
        if (grow < M) {
#pragma unroll
            for (int j = 0; j < 4; j++) {
                int gcol = bn * 128 + wn + j * 16 + q * 4;
                ushort4 s;
                s.x = f2b(acc[i][j][0]); s.y = f2b(acc[i][j][1]);
                s.z = f2b(acc[i][j][2]); s.w = f2b(acc[i][j][3]);
                *(ushort4*)(xw + (size_t)grow * 1024 + gcol) = s;
            }
        }
    }
}

// edge1csr: one wave per node.  lane=(p<<3)|sub: 8 edges/instr, ushort4 gathers.
__global__ __launch_bounds__(256) void edge1csr(const unsigned int* __restrict__ packed,
                                                const int* __restrict__ rowptr,
                                                const unsigned short* __restrict__ xw,
                                                const float* __restrict__ bias1,
                                                unsigned short* __restrict__ h1b) {
    __shared__ int hist[4 * 32];
    __shared__ unsigned int ebuf[4 * 64];
    __shared__ float vbuf[4 * 64];
    int wave = threadIdx.x >> 6, lane = threadIdx.x & 63;
    int f = blockIdx.x * 4 + wave;
    if (f >= N_NODES) return;
    int s = rowptr[f], k = rowptr[f + 1] - s;
    if (lane < 32) hist[wave * 32 + lane] = 0;
    for (int base = 0; base < k; base += 64) {
        int e = base + lane;
        if (e < k) atomicAdd(&hist[wave * 32 + (packed[s + e] >> 17)], 1);
    }
    int sub = lane & 7, p = lane >> 3;
    f32x4 acc = {0.f, 0.f, 0.f, 0.f};
    for (int base = 0; base < k; base += 64) {
        int e = base + lane;
        if (e < k) {
            unsigned int pk = packed[s + e];
            ebuf[wave * 64 + lane] = pk;
            vbuf[wave * 64 + lane] = 1.0f / (float)hist[wave * 32 + (pk >> 17)];
        }
        int cnum = min(64, k - base);
        int nst = (cnum + 7) >> 3;
#pragma unroll 4
        for (int i = 0; i < nst; i++) {
            int ei = (i << 3) + p;
            if (ei < cnum) {
                unsigned int pk = ebuf[wave * 64 + ei];
                float v = vbuf[wave * 64 + ei];
                int t_ = pk & 0x1FFFF, r = pk >> 17;
                ushort4 raw = *(const ushort4*)(xw + (size_t)t_ * 1024 + (r << 5) + (sub << 2));
                acc.x += v * b2f(raw.x); acc.y += v * b2f(raw.y);
                acc.z += v * b2f(raw.z); acc.w += v * b2f(raw.w);
            }
        }
    }
#pragma unroll
    for (int ofs = 8; ofs < 64; ofs <<= 1) {
        acc.x += __shfl_xor(acc.x, ofs, 64);
        acc.y += __shfl_xor(acc.y, ofs, 64);
        acc.z += __shfl_xor(acc.z, ofs, 64);
        acc.w += __shfl_xor(acc.w, ofs, 64);
    }
    if (p == 0) {
        int h = sub << 2;
        ushort4 o;
        o.x = f2b(fmaxf(acc.x + bias1[h + 0], 0.f));
        o.y = f2b(fmaxf(acc.y + bias1[h + 1], 0.f));
        o.z = f2b(fmaxf(acc.z + bias1[h + 2], 0.f));
        o.w = f2b(fmaxf(acc.w + bias1[h + 3], 0.f));
        *(ushort4*)(h1b + (size_t)f * 32 + h) = o;
    }
}

// GEMM2 (LDS-free): z[m][j2] = sum_h h1b[m][h]*w2T[j2][h].  K=32 (one MFMA step).
__global__ __launch_bounds__(256) void gemm2(const unsigned short* __restrict__ h1b,
                                             const unsigned short* __restrict__ w2T,
                                             unsigned short* __restrict__ z, int M) {
    int tid = threadIdx.x;
    int bn = blockIdx.x;            // 0..3
    int m0 = blockIdx.y * 128;
    int lane = tid & 63, wave = tid >> 6;
    int wm = (wave & 1) * 64, wn = (wave >> 1) * 64;
    int m_ = lane & 15, q = lane >> 4;
    f32x4 acc[4][4] = {};
    const unsigned short* Abase = h1b + (size_t)(m0 + wm + m_) * 32 + q * 8;
    const unsigned short* Bbase = w2T + (size_t)(bn * 128 + wn + m_) * 32 + q * 8;
    bf16x8 a[4], b[4];
#pragma unroll
    for (int i = 0; i < 4; i++)
        a[i] = *(const bf16x8*)(Abase + (size_t)i * 16 * 32);
#pragma unroll
    for (int j = 0; j < 4; j++)
        b[j] = *(const bf16x8*)(Bbase + (size_t)j * 16 * 32);
#pragma unroll
    for (int i = 0; i < 4; i++)
#pragma unroll
        for (int j = 0; j < 4; j++)
            acc[i][j] = __builtin_amdgcn_mfma_f32_16x16x32_bf16(b[j], a[i], acc[i][j], 0, 0, 0);
#pragma unroll
    for (int i = 0; i < 4; i++) {
        int grow = m0 + wm + i * 16 + m_;
        if (grow < M) {
#pragma unroll
            for (int j = 0; j < 4; j++) {
                int gcol = bn * 128 + wn + j * 16 + q * 4;
                ushort4 s;
                s.x = f2b(acc[i][j][0]); s.y = f2b(acc[i][j][1]);
                s.z = f2b(acc[i][j][2]); s.w = f2b(acc[i][j][3]);
                *(ushort4*)(z + (size_t)grow * 512 + gcol) = s;
            }
        }
    }
}

// edge2csr: one wave per node.  lane=(p<<2)|sub: 16 edges/instr, ushort4 gathers,
// float4 store with fused bias2.
__global__ __launch_bounds__(256) void edge2csr(const unsigned int* __restrict__ packed,
                                                const int* __restrict__ rowptr,
                                                const unsigned short* __restrict__ z,
                                                const float* __restrict__ bias2,
                                                float* __restrict__ out) {
    __shared__ int hist[4 * 32];
    __shared__ unsigned int ebuf[4 * 64];
    __shared__ float vbuf[4 * 64];
    int wave = threadIdx.x >> 6, lane = threadIdx.x & 63;
    int f = blockIdx.x * 4 + wave;
    if (f >= N_NODES) return;
    int s = rowptr[f], k = rowptr[f + 1] - s;
    if (lane < 32) hist[wave * 32 + lane] = 0;
    for (int base = 0; base < k; base += 64) {
        int e = base + lane;
        if (e < k) atomicAdd(&hist[wave * 32 + (packed[s + e] >> 17)], 1);
    }
    int sub = lane & 3, p = lane >> 2;
    f32x4 acc = {0.f, 0.f, 0.f, 0.f};
    for (int base = 0; base < k; base += 64) {
        int e = base + lane;
        if (e < k) {
            unsigned int pk = packed[s + e];
            ebuf[wave * 64 + lane] = pk;
            vbuf[wave * 64 + lane] = 1.0f / (float)hist[wave * 32 + (pk >> 17)];
        }
        int cnum = min(64, k - base);
        int nst = (cnum + 15) >> 4;
#pragma unroll 4
        for (int i = 0; i < nst; i++) {
            int ei = (i << 4) + p;
            if (ei < cnum) {
                unsigned int pk = ebuf[wave * 64 + ei];
                float v = vbuf[wave * 64 + ei];
                int t_ = pk & 0x1FFFF, r = pk >> 17;
                ushort4 raw = *(const ushort4*)(z + (size_t)t_ * 512 + (r << 4) + (sub << 2));
                acc.x += v * b2f(raw.x); acc.y += v * b2f(raw.y);
                acc.z += v * b2f(raw.z); acc.w += v * b2f(raw.w);
            }
        }
    }
#pragma unroll
    for (int ofs = 4; ofs < 64; ofs <<= 1) {
        acc.x += __shfl_xor(acc.x, ofs, 64);
        acc.y += __shfl_xor(acc.y, ofs, 64);
        acc.z += __shfl_xor(acc.z, ofs, 64);
        acc.w += __shfl_xor(acc.w, ofs, 64);
    }
    if (p == 0) {
        int c = sub << 2;
        float4 o;
        o.x = acc.x + bias2[c + 0];
        o.y = acc.y + bias2[c + 1];
        o.z = acc.z + bias2[c + 2];
        o.w = acc.w + bias2[c + 3];
        *(float4*)(out + (size_t)f * 16 + c) = o;
    }
}

extern "C" void kernel_launch(void* const* d_in, const int* in_sizes, int n_in,
                              void* d_out, int out_size, void* d_ws, size_t ws_size,
                              hipStream_t stream) {
    (void)in_sizes; (void)n_in; (void)out_size; (void)ws_size;
    const float* emb    = (const float*)d_in[0];
    const float* comps1 = (const float*)d_in[1];
    const float* bases1 = (const float*)d_in[2];
    const float* comps2 = (const float*)d_in[3];
    const float* bases2 = (const float*)d_in[4];
    const float* bias1  = (const float*)d_in[5];
    const float* bias2  = (const float*)d_in[6];
    const int* rel = (const int*)d_in[7];
    const int* fr  = (const int*)d_in[8];
    const int* to  = (const int*)d_in[9];
    float* out = (float*)d_out;
    char* ws = (char*)d_ws;

    // workspace layout (bytes); total ~250.3 MB
    int* gCursor         = (int*)(ws);                        // 1,568
    int* bucketBase      = (int*)(ws + 2048);                 // 1,568
    int* rowptr          = (int*)(ws + 4096);                 // 401,412
    unsigned int* packed = (unsigned int*)(ws + 406528);      // 12,800,000
    unsigned short* h1b  = (unsigned short*)(ws + 13206528);  // 6,406,144 (N_PAD x 32)
    unsigned short* w1T  = (unsigned short*)(ws + 19612672);  // 262,144
    unsigned short* w2T  = (unsigned short*)(ws + 19874816);  // 32,768
    unsigned short* embb = (unsigned short*)(ws + 19907584);  // 25,624,576 (N_PAD x 128)
    unsigned short* xw   = (unsigned short*)(ws + 45532160);  // 204,800,000
    unsigned short* z    = xw;                 // alias: xw dead before gemm2
    unsigned int* stage  = (unsigned int*)xw;  // alias: stage dead before gemm1
                                               //   (392*12288*4 = 19.3 MB < 204.8 MB)

    kcur<<<2, 256, 0, stream>>>(gCursor);
    kemb<<<6256, 256, 0, stream>>>(emb, embb);
    kw1<<<512, 256, 0, stream>>>(comps1, bases1, w1T);
    kw2<<<64, 256, 0, stream>>>(comps2, bases2, w2T);
    kbinA<<<196, 256, 0, stream>>>(rel, fr, to, gCursor, stage);
    kscan<<<1, 512, 0, stream>>>(gCursor, bucketBase);
    kscatter2<<<NB, 256, 0, stream>>>(stage, gCursor, bucketBase, rowptr, packed);
    gemm1<<<dim3(8, 782), 256, 0, stream>>>(embb, w1T, xw, N_NODES);
    edge1csr<<<25000, 256, 0, stream>>>(packed, rowptr, xw, bias1, h1b);
    gemm2<<<dim3(4, 782), 256, 0, stream>>>(h1b, w2T, z, N_NODES);
    edge2csr<<<25000, 256, 0, stream>>>(packed, rowptr, z, bias2, out);
}

// Round 6
// 549.913 us; speedup vs baseline: 6.0921x; 1.0080x over previous
//
#include <hip/hip_runtime.h>

// RGCN embedding, MI355X.  R6: XCD-aware swizzle on GEMMs (all 8 bn-blocks of
// a tile-row land on one XCD -> embb L2-resident, fetched once device-wide);
// deg packed into edge word (kscatter2 hist2) -> edge kernels lose their
// histogram pre-pass.  Atomic-free CSR throughout.
#define N_NODES 100000
#define N_PAD   100096         // 782*128 rows covered by GEMM grids
#define E_EDGES 3200000
#define NB      392            // buckets of 256 nodes: 392*256 = 100352 >= N+1
#define BCAP    12288          // mean 8192, sd ~90 -> cannot overflow
#define EPB     16384          // edges per kbinA block

typedef float f32x4 __attribute__((ext_vector_type(4)));
typedef __bf16 bf16x8 __attribute__((ext_vector_type(8)));

__device__ __forceinline__ float b2f(unsigned int u) {
    union { unsigned int i; float f; } x; x.i = u << 16; return x.f;
}
__device__ __forceinline__ unsigned short f2b(float f) {
    union { float f; unsigned int i; } x; x.f = f;
    unsigned int u = x.i + 0x7FFFu + ((x.i >> 16) & 1u);
    return (unsigned short)(u >> 16);
}

__global__ __launch_bounds__(256) void kcur(int* __restrict__ gCursor) {
    int id = blockIdx.x * 256 + threadIdx.x;
    if (id < NB) gCursor[id] = id * BCAP;
}

// emb f32 -> bf16, padded to N_PAD rows (pad = 0)
__global__ __launch_bounds__(256) void kemb(const float* __restrict__ emb,
                                            unsigned short* __restrict__ embb) {
    int id = blockIdx.x * 256 + threadIdx.x;     // 8 elements per thread
    if (id >= N_PAD * 128 / 8) return;
    size_t base = (size_t)id * 8;
    ushort4 o0 = {0, 0, 0, 0}, o1 = {0, 0, 0, 0};
    if (base < (size_t)N_NODES * 128) {
        float4 v0 = *(const float4*)(emb + base);
        float4 v1 = *(const float4*)(emb + base + 4);
        o0.x = f2b(v0.x); o0.y = f2b(v0.y); o0.z = f2b(v0.z); o0.w = f2b(v0.w);
        o1.x = f2b(v1.x); o1.y = f2b(v1.y); o1.z = f2b(v1.z); o1.w = f2b(v1.w);
    }
    *(ushort4*)(embb + base) = o0;
    *(ushort4*)(embb + base + 4) = o1;
}

// w1T[j][k] = sum_b comps1[r,b]*bases1[b,k,h], j=r*32+h  (bf16, [1024][128])
__global__ __launch_bounds__(256) void kw1(const float* __restrict__ comps1,
                                           const float* __restrict__ bases1,
                                           unsigned short* __restrict__ w1T) {
    int id = blockIdx.x * 256 + threadIdx.x;
    if (id >= 1024 * 128) return;
    int k = id & 127, j = id >> 7;
    int r = j >> 5, h = j & 31;
    float s = 0.f;
#pragma unroll
    for (int b = 0; b < 16; b++)
        s += comps1[r * 16 + b] * bases1[b * 4096 + k * 32 + h];
    w1T[(size_t)j * 128 + k] = f2b(s);
}

// w2T[j2][h] = sum_b comps2[r,b]*bases2[b,h,c], j2=r*16+c  (bf16, [512][32])
__global__ __launch_bounds__(256) void kw2(const float* __restrict__ comps2,
                                           const float* __restrict__ bases2,
                                           unsigned short* __restrict__ w2T) {
    int id = blockIdx.x * 256 + threadIdx.x;
    if (id >= 512 * 32) return;
    int h = id & 31, j = id >> 5;
    int r = j >> 4, c = j & 15;
    float s = 0.f;
#pragma unroll
    for (int b = 0; b < 16; b++)
        s += comps2[r * 16 + b] * bases2[b * 512 + h * 16 + c];
    w2T[(size_t)j * 32 + h] = f2b(s);
}

// Bin edges into per-bucket stage regions.  stage word = (frlo<<22)|(rel<<17)|to.
__global__ __launch_bounds__(256) void kbinA(const int* __restrict__ rel,
                                             const int* __restrict__ fr,
                                             const int* __restrict__ to,
                                             int* __restrict__ gCursor,
                                             unsigned int* __restrict__ stage) {
    __shared__ int cnt[NB];
    __shared__ int base[NB];
    int tid = threadIdx.x;
    int e0 = blockIdx.x * EPB;
    for (int i = tid; i < NB; i += 256) cnt[i] = 0;
    __syncthreads();
#pragma unroll 4
    for (int i = 0; i < EPB / 256; i++) {
        int e = e0 + i * 256 + tid;
        if (e < E_EDGES) atomicAdd(&cnt[fr[e] >> 8], 1);
    }
    __syncthreads();
    for (int i = tid; i < NB; i += 256) {
        base[i] = atomicAdd(&gCursor[i], cnt[i]);
        cnt[i] = 0;
    }
    __syncthreads();
#pragma unroll 4
    for (int i = 0; i < EPB / 256; i++) {
        int e = e0 + i * 256 + tid;
        if (e < E_EDGES) {
            int f = fr[e];
            int b = f >> 8;
            int rank = atomicAdd(&cnt[b], 1);
            stage[base[b] + rank] =
                ((unsigned int)(f & 255) << 22) | ((unsigned int)rel[e] << 17) | (unsigned int)to[e];
        }
    }
}

// exclusive scan of bucket counts (from cursors) -> bucketBase
__global__ __launch_bounds__(512) void kscan(const int* __restrict__ gCursor,
                                             int* __restrict__ bucketBase) {
    __shared__ int a[512], b[512];
    int t = threadIdx.x;
    int v = (t < NB) ? (gCursor[t] - t * BCAP) : 0;
    a[t] = v;
    __syncthreads();
    int* src = a; int* dst = b;
    for (int ofs = 1; ofs < 512; ofs <<= 1) {
        int x = src[t];
        if (t >= ofs) x += src[t - ofs];
        __syncthreads();
        dst[t] = x;
        __syncthreads();
        int* tmp = src; src = dst; dst = tmp;
    }
    if (t < NB) bucketBase[t] = src[t] - v;
}

// Per-bucket: LDS node-hist -> scan -> rowptr; LDS (node,rel)-hist -> deg;
// scatter packed = (deg<<22)|(rel<<17)|to.  Zero global atomics.
__global__ __launch_bounds__(256) void kscatter2(const unsigned int* __restrict__ stage,
                                                 const int* __restrict__ gCursor,
                                                 const int* __restrict__ bucketBase,
                                                 int* __restrict__ rowptr,
                                                 unsigned int* __restrict__ packed) {
    __shared__ int hist[256], hexcl[256], rk[256], sa[256], sb[256];
    __shared__ int hist2[256 * 32];
    int b = blockIdx.x, t = threadIdx.x;
    int nb = gCursor[b] - b * BCAP;
    int sbase = b * BCAP;
    int gbase = bucketBase[b];
    hist[t] = 0; rk[t] = 0;
    for (int i = t; i < 256 * 32; i += 256) hist2[i] = 0;
    __syncthreads();
    for (int i = t; i < nb; i += 256) {
        unsigned int pk = stage[sbase + i];
        atomicAdd(&hist[pk >> 22], 1);
        atomicAdd(&hist2[((pk >> 22) << 5) | ((pk >> 17) & 31)], 1);
    }
    __syncthreads();
    int v = hist[t];
    sa[t] = v;
    __syncthreads();
    int* src = sa; int* dst = sb;
    for (int ofs = 1; ofs < 256; ofs <<= 1) {
        int x = src[t];
        if (t >= ofs) x += src[t - ofs];
        __syncthreads();
        dst[t] = x;
        __syncthreads();
        int* tmp = src; src = dst; dst = tmp;
    }
    int excl = src[t] - v;
    hexcl[t] = excl;
    rowptr[b * 256 + t] = gbase + excl;
    __syncthreads();
    for (int i = t; i < nb; i += 256) {
        unsigned int pk = stage[sbase + i];
        int frlo = pk >> 22;
        int rank = atomicAdd(&rk[frlo], 1);
        int dg = min(hist2[(frlo << 5) | ((pk >> 17) & 31)], 1023);
        packed[gbase + hexcl[frlo] + rank] = ((unsigned int)dg << 22) | (pk & 0x3FFFFFu);
    }
}

// GEMM1 (LDS-free, XCD-swizzled): xw[m][j] = sum_k embb[m][k]*w1T[j][k].
// xcd=id&7, y=8*(w>>3)+xcd: the 8 bn-blocks of a tile-row are consecutive
// within-XCD slots -> A tile read once per XCD, L2-resident.
__global__ __launch_bounds__(256) void gemm1(const unsigned short* __restrict__ embb,
                                             const unsigned short* __restrict__ w1T,
                                             unsigned short* __restrict__ xw, int M) {
    int id = blockIdx.x;
    int xcd = id & 7, w = id >> 3;
    int ty = w >> 3, bn = w & 7;
    int y = ty * 8 + xcd;
    if (y >= 782) return;
    int m0 = y * 128;
    int tid = threadIdx.x;
    int lane = tid & 63, wave = tid >> 6;
    int wm = (wave & 1) * 64, wn = (wave >> 1) * 64;
    int m_ = lane & 15, q = lane >> 4;
    f32x4 acc[4][4] = {};
    const unsigned short* Abase = embb + (size_t)(m0 + wm + m_) * 128 + q * 8;
    const unsigned short* Bbase = w1T + (size_t)(bn * 128 + wn + m_) * 128 + q * 8;
#pragma unroll
    for (int k0 = 0; k0 < 128; k0 += 32) {
        bf16x8 a[4], b[4];
#pragma unroll
        for (int i = 0; i < 4; i++)
            a[i] = *(const bf16x8*)(Abase + (size_t)i * 16 * 128 + k0);
#pragma unroll
        for (int j = 0; j < 4; j++)
            b[j] = *(const bf16x8*)(Bbase + (size_t)j * 16 * 128 + k0);
#pragma unroll
        for (int i = 0; i < 4; i++)
#pragma unroll
            for (int j = 0; j < 4; j++)
                acc[i][j] = __builtin_amdgcn_mfma_f32_16x16x32_bf16(b[j], a[i], acc[i][j], 0, 0, 0);
    }
#pragma unroll
    for (int i = 0; i < 4; i++) {
        int grow = m0 + wm + i * 16 + m_;
        if (grow < M) {
#pragma unroll
            for (int j = 0; j < 4; j++) {
                int gcol = bn * 128 + wn + j * 16 + q * 4;
                ushort4 s;
                s.x = f2b(acc[i][j][0]); s.y = f2b(acc[i][j][1]);
                s.z = f2b(acc[i][j][2]); s.w = f2b(acc[i][j][3]);
                *(ushort4*)(xw + (size_t)grow * 1024 + gcol) = s;
            }
        }
    }
}

// edge1csr: one wave per node, single pass (deg comes packed).
// lane=(p<<3)|sub: 8 edges/instr, ushort4 gathers; fused bias1+relu store.
__global__ __launch_bounds__(256) void edge1csr(const unsigned int* __restrict__ packed,
                                                const int* __restrict__ rowptr,
                                                const unsigned short* __restrict__ xw,
                                                const float* __restrict__ bias1,
                                                unsigned short* __restrict__ h1b) {
    __shared__ unsigned int ebuf[4 * 64];
    __shared__ float vbuf[4 * 64];
    int wave = threadIdx.x >> 6, lane = threadIdx.x & 63;
    int f = blockIdx.x * 4 + wave;
    if (f >= N_NODES) return;
    int s = rowptr[f], k = rowptr[f + 1] - s;
    int sub = lane & 7, p = lane >> 3;
    f32x4 acc = {0.f, 0.f, 0.f, 0.f};
    for (int base = 0; base < k; base += 64) {
        int e = base + lane;
        if (e < k) {
            unsigned int pk = packed[s + e];
            ebuf[wave * 64 + lane] = pk;
            vbuf[wave * 64 + lane] = 1.0f / (float)(pk >> 22);
        }
        int cnum = min(64, k - base);
        int nst = (cnum + 7) >> 3;
#pragma unroll 4
        for (int i = 0; i < nst; i++) {
            int ei = (i << 3) + p;
            if (ei < cnum) {
                unsigned int pk = ebuf[wave * 64 + ei];
                float v = vbuf[wave * 64 + ei];
                int t_ = pk & 0x1FFFF, r = (pk >> 17) & 31;
                ushort4 raw = *(const ushort4*)(xw + (size_t)t_ * 1024 + (r << 5) + (sub << 2));
                acc.x += v * b2f(raw.x); acc.y += v * b2f(raw.y);
                acc.z += v * b2f(raw.z); acc.w += v * b2f(raw.w);
            }
        }
    }
#pragma unroll
    for (int ofs = 8; ofs < 64; ofs <<= 1) {
        acc.x += __shfl_xor(acc.x, ofs, 64);
        acc.y += __shfl_xor(acc.y, ofs, 64);
        acc.z += __shfl_xor(acc.z, ofs, 64);
        acc.w += __shfl_xor(acc.w, ofs, 64);
    }
    if (p == 0) {
        int h = sub << 2;
        ushort4 o;
        o.x = f2b(fmaxf(acc.x + bias1[h + 0], 0.f));
        o.y = f2b(fmaxf(acc.y + bias1[h + 1], 0.f));
        o.z = f2b(fmaxf(acc.z + bias1[h + 2], 0.f));
        o.w = f2b(fmaxf(acc.w + bias1[h + 3], 0.f));
        *(ushort4*)(h1b + (size_t)f * 32 + h) = o;
    }
}

// GEMM2 (LDS-free, XCD-swizzled): z[m][j2] = sum_h h1b[m][h]*w2T[j2][h].
__global__ __launch_bounds__(256) void gemm2(const unsigned short* __restrict__ h1b,
                                             const unsigned short* __restrict__ w2T,
                                             unsigned short* __restrict__ z, int M) {
    int id = blockIdx.x;
    int xcd = id & 7, w = id >> 3;
    int ty = w >> 2, bn = w & 3;
    int y = ty * 8 + xcd;
    if (y >= 782) return;
    int m0 = y * 128;
    int tid = threadIdx.x;
    int lane = tid & 63, wave = tid >> 6;
    int wm = (wave & 1) * 64, wn = (wave >> 1) * 64;
    int m_ = lane & 15, q = lane >> 4;
    f32x4 acc[4][4] = {};
    const unsigned short* Abase = h1b + (size_t)(m0 + wm + m_) * 32 + q * 8;
    const unsigned short* Bbase = w2T + (size_t)(bn * 128 + wn + m_) * 32 + q * 8;
    bf16x8 a[4], b[4];
#pragma unroll
    for (int i = 0; i < 4; i++)
        a[i] = *(const bf16x8*)(Abase + (size_t)i * 16 * 32);
#pragma unroll
    for (int j = 0; j < 4; j++)
        b[j] = *(const bf16x8*)(Bbase + (size_t)j * 16 * 32);
#pragma unroll
    for (int i = 0; i < 4; i++)
#pragma unroll
        for (int j = 0; j < 4; j++)
            acc[i][j] = __builtin_amdgcn_mfma_f32_16x16x32_bf16(b[j], a[i], acc[i][j], 0, 0, 0);
#pragma unroll
    for (int i = 0; i < 4; i++) {
        int grow = m0 + wm + i * 16 + m_;
        if (grow < M) {
#pragma unroll
            for (int j = 0; j < 4; j++) {
                int gcol = bn * 128 + wn + j * 16 + q * 4;
                ushort4 s;
                s.x = f2b(acc[i][j][0]); s.y = f2b(acc[i][j][1]);
                s.z = f2b(acc[i][j][2]); s.w = f2b(acc[i][j][3]);
                *(ushort4*)(z + (size_t)grow * 512 + gcol) = s;
            }
        }
    }
}

// edge2csr: one wave per node, single pass.  lane=(p<<2)|sub: 16 edges/instr,
// ushort4 gathers, float4 store with fused bias2.
__global__ __launch_bounds__(256) void edge2csr(const unsigned int* __restrict__ packed,
                                                const int* __restrict__ rowptr,
                                                const unsigned short* __restrict__ z,
                                                const float* __restrict__ bias2,
                                                float* __restrict__ out) {
    __shared__ unsigned int ebuf[4 * 64];
    __shared__ float vbuf[4 * 64];
    int wave = threadIdx.x >> 6, lane = threadIdx.x & 63;
    int f = blockIdx.x * 4 + wave;
    if (f >= N_NODES) return;
    int s = rowptr[f], k = rowptr[f + 1] - s;
    int sub = lane & 3, p = lane >> 2;
    f32x4 acc = {0.f, 0.f, 0.f, 0.f};
    for (int base = 0; base < k; base += 64) {
        int e = base + lane;
        if (e < k) {
            unsigned int pk = packed[s + e];
            ebuf[wave * 64 + lane] = pk;
            vbuf[wave * 64 + lane] = 1.0f / (float)(pk >> 22);
        }
        int cnum = min(64, k - base);
        int nst = (cnum + 15) >> 4;
#pragma unroll 4
        for (int i = 0; i < nst; i++) {
            int ei = (i << 4) + p;
            if (ei < cnum) {
                unsigned int pk = ebuf[wave * 64 + ei];
                float v = vbuf[wave * 64 + ei];
                int t_ = pk & 0x1FFFF, r = (pk >> 17) & 31;
                ushort4 raw = *(const ushort4*)(z + (size_t)t_ * 512 + (r << 4) + (sub << 2));
                acc.x += v * b2f(raw.x); acc.y += v * b2f(raw.y);
                acc.z += v * b2f(raw.z); acc.w += v * b2f(raw.w);
            }
        }
    }
#pragma unroll
    for (int ofs = 4; ofs < 64; ofs <<= 1) {
        acc.x += __shfl_xor(acc.x, ofs, 64);
        acc.y += __shfl_xor(acc.y, ofs, 64);
        acc.z += __shfl_xor(acc.z, ofs, 64);
        acc.w += __shfl_xor(acc.w, ofs, 64);
    }
    if (p == 0) {
        int c = sub << 2;
        float4 o;
        o.x = acc.x + bias2[c + 0];
        o.y = acc.y + bias2[c + 1];
        o.z = acc.z + bias2[c + 2];
        o.w = acc.w + bias2[c + 3];
        *(float4*)(out + (size_t)f * 16 + c) = o;
    }
}

extern "C" void kernel_launch(void* const* d_in, const int* in_sizes, int n_in,
                              void* d_out, int out_size, void* d_ws, size_t ws_size,
                              hipStream_t stream) {
    (void)in_sizes; (void)n_in; (void)out_size; (void)ws_size;
    const float* emb    = (const float*)d_in[0];
    const float* comps1 = (const float*)d_in[1];
    const float* bases1 = (const float*)d_in[2];
    const float* comps2 = (const float*)d_in[3];
    const float* bases2 = (const float*)d_in[4];
    const float* bias1  = (const float*)d_in[5];
    const float* bias2  = (const float*)d_in[6];
    const int* rel = (const int*)d_in[7];
    const int* fr  = (const int*)d_in[8];
    const int* to  = (const int*)d_in[9];
    float* out = (float*)d_out;
    char* ws = (char*)d_ws;

    // workspace layout (bytes); total ~250.3 MB
    int* gCursor         = (int*)(ws);                        // 1,568
    int* bucketBase      = (int*)(ws + 2048);                 // 1,568
    int* rowptr          = (int*)(ws + 4096);                 // 401,412
    unsigned int* packed = (unsigned int*)(ws + 406528);      // 12,800,000
    unsigned short* h1b  = (unsigned short*)(ws + 13206528);  // 6,406,144 (N_PAD x 32)
    unsigned short* w1T  = (unsigned short*)(ws + 19612672);  // 262,144
    unsigned short* w2T  = (unsigned short*)(ws + 19874816);  // 32,768
    unsigned short* embb = (unsigned short*)(ws + 19907584);  // 25,624,576 (N_PAD x 128)
    unsigned short* xw   = (unsigned short*)(ws + 45532160);  // 204,800,000
    unsigned short* z    = xw;                 // alias: xw dead before gemm2
    unsigned int* stage  = (unsigned int*)xw;  // alias: stage dead before gemm1
                                               //   (392*12288*4 = 19.3 MB < 204.8 MB)

    kcur<<<2, 256, 0, stream>>>(gCursor);
    kemb<<<6256, 256, 0, stream>>>(emb, embb);
    kw1<<<512, 256, 0, stream>>>(comps1, bases1, w1T);
    kw2<<<64, 256, 0, stream>>>(comps2, bases2, w2T);
    kbinA<<<196, 256, 0, stream>>>(rel, fr, to, gCursor, stage);
    kscan<<<1, 512, 0, stream>>>(gCursor, bucketBase);
    kscatter2<<<NB, 256, 0, stream>>>(stage, gCursor, bucketBase, rowptr, packed);
    gemm1<<<6272, 256, 0, stream>>>(embb, w1T, xw, N_NODES);     // 8 xcd * 98 ty * 8 bn
    edge1csr<<<25000, 256, 0, stream>>>(packed, rowptr, xw, bias1, h1b);
    gemm2<<<3136, 256, 0, stream>>>(h1b, w2T, z, N_NODES);       // 8 xcd * 98 ty * 4 bn
    edge2csr<<<25000, 256, 0, stream>>>(packed, rowptr, z, bias2, out);
}

// Round 7
// 523.404 us; speedup vs baseline: 6.4006x; 1.0506x over previous
//
#include <hip/hip_runtime.h>

// RGCN embedding, MI355X.  R7: streaming-wave GEMMs — B-slab resident in
// registers, ping-pong A prefetch across m-iters (latency hidden in-wave),
// XCD-swizzled m-groups.  CSR build + edge passes unchanged from R6.
#define N_NODES 100000
#define N_PAD   100096
#define E_EDGES 3200000
#define NB      392            // buckets of 256 nodes
#define BCAP    12288
#define EPB     16384

typedef float f32x4 __attribute__((ext_vector_type(4)));
typedef __bf16 bf16x8 __attribute__((ext_vector_type(8)));

__device__ __forceinline__ float b2f(unsigned int u) {
    union { unsigned int i; float f; } x; x.i = u << 16; return x.f;
}
__device__ __forceinline__ unsigned short f2b(float f) {
    union { float f; unsigned int i; } x; x.f = f;
    unsigned int u = x.i + 0x7FFFu + ((x.i >> 16) & 1u);
    return (unsigned short)(u >> 16);
}

__global__ __launch_bounds__(256) void kcur(int* __restrict__ gCursor) {
    int id = blockIdx.x * 256 + threadIdx.x;
    if (id < NB) gCursor[id] = id * BCAP;
}

// emb f32 -> bf16, padded to N_PAD rows (pad = 0)
__global__ __launch_bounds__(256) void kemb(const float* __restrict__ emb,
                                            unsigned short* __restrict__ embb) {
    int id = blockIdx.x * 256 + threadIdx.x;
    if (id >= N_PAD * 128 / 8) return;
    size_t base = (size_t)id * 8;
    ushort4 o0 = {0, 0, 0, 0}, o1 = {0, 0, 0, 0};
    if (base < (size_t)N_NODES * 128) {
        float4 v0 = *(const float4*)(emb + base);
        float4 v1 = *(const float4*)(emb + base + 4);
        o0.x = f2b(v0.x); o0.y = f2b(v0.y); o0.z = f2b(v0.z); o0.w = f2b(v0.w);
        o1.x = f2b(v1.x); o1.y = f2b(v1.y); o1.z = f2b(v1.z); o1.w = f2b(v1.w);
    }
    *(ushort4*)(embb + base) = o0;
    *(ushort4*)(embb + base + 4) = o1;
}

// w1T[j][k] = sum_b comps1[r,b]*bases1[b,k,h], j=r*32+h  (bf16, [1024][128])
__global__ __launch_bounds__(256) void kw1(const float* __restrict__ comps1,
                                           const float* __restrict__ bases1,
                                           unsigned short* __restrict__ w1T) {
    int id = blockIdx.x * 256 + threadIdx.x;
    if (id >= 1024 * 128) return;
    int k = id & 127, j = id >> 7;
    int r = j >> 5, h = j & 31;
    float s = 0.f;
#pragma unroll
    for (int b = 0; b < 16; b++)
        s += comps1[r * 16 + b] * bases1[b * 4096 + k * 32 + h];
    w1T[(size_t)j * 128 + k] = f2b(s);
}

// w2T[j2][h] = sum_b comps2[r,b]*bases2[b,h,c], j2=r*16+c  (bf16, [512][32])
__global__ __launch_bounds__(256) void kw2(const float* __restrict__ comps2,
                                           const float* __restrict__ bases2,
                                           unsigned short* __restrict__ w2T) {
    int id = blockIdx.x * 256 + threadIdx.x;
    if (id >= 512 * 32) return;
    int h = id & 31, j = id >> 5;
    int r = j >> 4, c = j & 15;
    float s = 0.f;
#pragma unroll
    for (int b = 0; b < 16; b++)
        s += comps2[r * 16 + b] * bases2[b * 512 + h * 16 + c];
    w2T[(size_t)j * 32 + h] = f2b(s);
}

// Bin edges by fr>>8 into per-bucket stage regions.  word=(frlo<<22)|(rel<<17)|to.
__global__ __launch_bounds__(256) void kbinA(const int* __restrict__ rel,
                                             const int* __restrict__ fr,
                                             const int* __restrict__ to,
                                             int* __restrict__ gCursor,
                                             unsigned int* __restrict__ stage) {
    __shared__ int cnt[NB];
    __shared__ int base[NB];
    int tid = threadIdx.x;
    int e0 = blockIdx.x * EPB;
    for (int i = tid; i < NB; i += 256) cnt[i] = 0;
    __syncthreads();
#pragma unroll 4
    for (int i = 0; i < EPB / 256; i++) {
        int e = e0 + i * 256 + tid;
        if (e < E_EDGES) atomicAdd(&cnt[fr[e] >> 8], 1);
    }
    __syncthreads();
    for (int i = tid; i < NB; i += 256) {
        base[i] = atomicAdd(&gCursor[i], cnt[i]);
        cnt[i] = 0;
    }
    __syncthreads();
#pragma unroll 4
    for (int i = 0; i < EPB / 256; i++) {
        int e = e0 + i * 256 + tid;
        if (e < E_EDGES) {
            int f = fr[e];
            int b = f >> 8;
            int rank = atomicAdd(&cnt[b], 1);
            stage[base[b] + rank] =
                ((unsigned int)(f & 255) << 22) | ((unsigned int)rel[e] << 17) | (unsigned int)to[e];
        }
    }
}

// exclusive scan of bucket counts -> bucketBase
__global__ __launch_bounds__(512) void kscan(const int* __restrict__ gCursor,
                                             int* __restrict__ bucketBase) {
    __shared__ int a[512], b[512];
    int t = threadIdx.x;
    int v = (t < NB) ? (gCursor[t] - t * BCAP) : 0;
    a[t] = v;
    __syncthreads();
    int* src = a; int* dst = b;
    for (int ofs = 1; ofs < 512; ofs <<= 1) {
        int x = src[t];
        if (t >= ofs) x += src[t - ofs];
        __syncthreads();
        dst[t] = x;
        __syncthreads();
        int* tmp = src; src = dst; dst = tmp;
    }
    if (t < NB) bucketBase[t] = src[t] - v;
}

// Per-bucket: LDS node-hist -> scan -> rowptr; (node,rel)-hist -> deg;
// scatter packed = (deg<<22)|(rel<<17)|to.
__global__ __launch_bounds__(256) void kscatter2(const unsigned int* __restrict__ stage,
                                                 const int* __restrict__ gCursor,
                                                 const int* __restrict__ bucketBase,
                                                 int* __restrict__ rowptr,
                                                 unsigned int* __restrict__ packed) {
    __shared__ int hist[256], hexcl[256], rk[256], sa[256], sb[256];
    __shared__ int hist2[256 * 32];
    int b = blockIdx.x, t = threadIdx.x;
    int nb = gCursor[b] - b * BCAP;
    int sbase = b * BCAP;
    int gbase = bucketBase[b];
    hist[t] = 0; rk[t] = 0;
    for (int i = t; i < 256 * 32; i += 256) hist2[i] = 0;
    __syncthreads();
    for (int i = t; i < nb; i += 256) {
        unsigned int pk = stage[sbase + i];
        atomicAdd(&hist[pk >> 22], 1);
        atomicAdd(&hist2[((pk >> 22) << 5) | ((pk >> 17) & 31)], 1);
    }
    __syncthreads();
    int v = hist[t];
    sa[t] = v;
    __syncthreads();
    int* src = sa; int* dst = sb;
    for (int ofs = 1; ofs < 256; ofs <<= 1) {
        int x = src[t];
        if (t >= ofs) x += src[t - ofs];
        __syncthreads();
        dst[t] = x;
        __syncthreads();
        int* tmp = src; src = dst; dst = tmp;
    }
    int excl = src[t] - v;
    hexcl[t] = excl;
    rowptr[b * 256 + t] = gbase + excl;
    __syncthreads();
    for (int i = t; i < nb; i += 256) {
        unsigned int pk = stage[sbase + i];
        int frlo = pk >> 22;
        int rank = atomicAdd(&rk[frlo], 1);
        int dg = min(hist2[(frlo << 5) | ((pk >> 17) & 31)], 1023);
        packed[gbase + hexcl[frlo] + rank] = ((unsigned int)dg << 22) | (pk & 0x3FFFFFu);
    }
}

// GEMM1 (streaming-wave): xw[m][j] = sum_k embb[m][k]*w1T[j][k].
// Wave: B-slab 64n x 128k resident (16 frags); 16 m-iters of 16 rows each
// with ping-pong A prefetch.  Block = 4 waves (64 rows/iter), 1024 rows total.
// Grid: 8 xcd * 16 bn * 13 mgl; mg = mgl*8+xcd keeps an m-group's 16 bn-blocks
// on one XCD (A read once per device).
__global__ __launch_bounds__(256) void gemm1(const unsigned short* __restrict__ embb,
                                             const unsigned short* __restrict__ w1T,
                                             unsigned short* __restrict__ xw) {
    int id = blockIdx.x;
    int xcd = id & 7, w = id >> 3;
    int bn = w & 15, mgl = w >> 4;
    int mg = mgl * 8 + xcd;
    if (mg >= 98) return;
    int lane = threadIdx.x & 63, wave = threadIdx.x >> 6;
    int m_ = lane & 15, q = lane >> 4;
    bf16x8 B[4][4];
    const unsigned short* Bbase = w1T + (size_t)(bn * 64 + m_) * 128 + q * 8;
#pragma unroll
    for (int j = 0; j < 4; j++)
#pragma unroll
        for (int k0 = 0; k0 < 4; k0++)
            B[j][k0] = *(const bf16x8*)(Bbase + j * 16 * 128 + k0 * 32);
    int mrow0 = mg * 1024 + wave * 16;              // wave's first row block
    const unsigned short* Abase = embb + (size_t)(mrow0 + m_) * 128 + q * 8;
    bf16x8 a0[4], a1[4];
    if (mrow0 < N_PAD) {
#pragma unroll
        for (int k0 = 0; k0 < 4; k0++)
            a0[k0] = *(const bf16x8*)(Abase + k0 * 32);
    }
#pragma unroll
    for (int t = 0; t < 16; t++) {
        int m0 = mrow0 + t * 64;
        if (m0 >= N_PAD) break;
        bf16x8* acur = (t & 1) ? a1 : a0;
        bf16x8* anext = (t & 1) ? a0 : a1;
        if (t < 15 && m0 + 64 < N_PAD) {
#pragma unroll
            for (int k0 = 0; k0 < 4; k0++)
                anext[k0] = *(const bf16x8*)(Abase + (size_t)(t + 1) * 64 * 128 + k0 * 32);
        }
        f32x4 acc[4] = {};
#pragma unroll
        for (int k0 = 0; k0 < 4; k0++)
#pragma unroll
            for (int j = 0; j < 4; j++)
                acc[j] = __builtin_amdgcn_mfma_f32_16x16x32_bf16(B[j][k0], acur[k0], acc[j], 0, 0, 0);
        int grow = m0 + m_;
        if (grow < N_NODES) {
#pragma unroll
            for (int j = 0; j < 4; j++) {
                ushort4 s;
                s.x = f2b(acc[j][0]); s.y = f2b(acc[j][1]);
                s.z = f2b(acc[j][2]); s.w = f2b(acc[j][3]);
                *(ushort4*)(xw + (size_t)grow * 1024 + bn * 64 + j * 16 + q * 4) = s;
            }
        }
    }
}

// edge1csr: one wave per node, single pass (deg packed).  8 edges/instr.
__global__ __launch_bounds__(256) void edge1csr(const unsigned int* __restrict__ packed,
                                                const int* __restrict__ rowptr,
                                                const unsigned short* __restrict__ xw,
                                                const float* __restrict__ bias1,
                                                unsigned short* __restrict__ h1b) {
    __shared__ unsigned int ebuf[4 * 64];
    __shared__ float vbuf[4 * 64];
    int wave = threadIdx.x >> 6, lane = threadIdx.x & 63;
    int f = blockIdx.x * 4 + wave;
    if (f >= N_NODES) return;
    int s = rowptr[f], k = rowptr[f + 1] - s;
    int sub = lane & 7, p = lane >> 3;
    f32x4 acc = {0.f, 0.f, 0.f, 0.f};
    for (int base = 0; base < k; base += 64) {
        int e = base + lane;
        if (e < k) {
            unsigned int pk = packed[s + e];
            ebuf[wave * 64 + lane] = pk;
            vbuf[wave * 64 + lane] = 1.0f / (float)(pk >> 22);
        }
        int cnum = min(64, k - base);
        int nst = (cnum + 7) >> 3;
#pragma unroll 4
        for (int i = 0; i < nst; i++) {
            int ei = (i << 3) + p;
            if (ei < cnum) {
                unsigned int pk = ebuf[wave * 64 + ei];
                float v = vbuf[wave * 64 + ei];
                int t_ = pk & 0x1FFFF, r = (pk >> 17) & 31;
                ushort4 raw = *(const ushort4*)(xw + (size_t)t_ * 1024 + (r << 5) + (sub << 2));
                acc.x += v * b2f(raw.x); acc.y += v * b2f(raw.y);
                acc.z += v * b2f(raw.z); acc.w += v * b2f(raw.w);
            }
        }
    }
#pragma unroll
    for (int ofs = 8; ofs < 64; ofs <<= 1) {
        acc.x += __shfl_xor(acc.x, ofs, 64);
        acc.y += __shfl_xor(acc.y, ofs, 64);
        acc.z += __shfl_xor(acc.z, ofs, 64);
        acc.w += __shfl_xor(acc.w, ofs, 64);
    }
    if (p == 0) {
        int h = sub << 2;
        ushort4 o;
        o.x = f2b(fmaxf(acc.x + bias1[h + 0], 0.f));
        o.y = f2b(fmaxf(acc.y + bias1[h + 1], 0.f));
        o.z = f2b(fmaxf(acc.z + bias1[h + 2], 0.f));
        o.w = f2b(fmaxf(acc.w + bias1[h + 3], 0.f));
        *(ushort4*)(h1b + (size_t)f * 32 + h) = o;
    }
}

// GEMM2 (streaming-wave): z[m][j2] = sum_h h1b[m][h]*w2T[j2][h].  K=32.
// Wave: B-slab 64n x 32k resident (4 frags); 8 m-iters of 32 rows.
__global__ __launch_bounds__(256) void gemm2(const unsigned short* __restrict__ h1b,
                                             const unsigned short* __restrict__ w2T,
                                             unsigned short* __restrict__ z) {
    int id = blockIdx.x;
    int xcd = id & 7, w = id >> 3;
    int bn = w & 7, mgl = w >> 3;
    int mg = mgl * 8 + xcd;
    if (mg >= 98) return;
    int lane = threadIdx.x & 63, wave = threadIdx.x >> 6;
    int m_ = lane & 15, q = lane >> 4;
    bf16x8 B[4];
    const unsigned short* Bbase = w2T + (size_t)(bn * 64 + m_) * 32 + q * 8;
#pragma unroll
    for (int j = 0; j < 4; j++)
        B[j] = *(const bf16x8*)(Bbase + j * 16 * 32);
    int mrow0 = mg * 1024 + wave * 32;
    const unsigned short* Abase = h1b + (size_t)(mrow0 + m_) * 32 + q * 8;
    bf16x8 a0[2], a1[2];
    if (mrow0 < N_PAD) {
        a0[0] = *(const bf16x8*)(Abase);
        a0[1] = *(const bf16x8*)(Abase + 16 * 32);
    }
#pragma unroll
    for (int t = 0; t < 8; t++) {
        int m0 = mrow0 + t * 128;
        if (m0 >= N_PAD) break;
        bf16x8* acur = (t & 1) ? a1 : a0;
        bf16x8* anext = (t & 1) ? a0 : a1;
        if (t < 7 && m0 + 128 < N_PAD) {
            anext[0] = *(const bf16x8*)(Abase + (size_t)(t + 1) * 128 * 32);
            anext[1] = *(const bf16x8*)(Abase + (size_t)(t + 1) * 128 * 32 + 16 * 32);
        }
        f32x4 acc[2][4] = {};
#pragma unroll
        for (int i = 0; i < 2; i++)
#pragma unroll
            for (int j = 0; j < 4; j++)
                acc[i][j] = __builtin_amdgcn_mfma_f32_16x16x32_bf16(B[j], acur[i], acc[i][j], 0, 0, 0);
#pragma unroll
        for (int i = 0; i < 2; i++) {
            int grow = m0 + i * 16 + m_;
            if (grow < N_NODES) {
#pragma unroll
                for (int j = 0; j < 4; j++) {
                    ushort4 s;
                    s.x = f2b(acc[i][j][0]); s.y = f2b(acc[i][j][1]);
                    s.z = f2b(acc[i][j][2]); s.w = f2b(acc[i][j][3]);
                    *(ushort4*)(z + (size_t)grow * 512 + bn * 64 + j * 16 + q * 4) = s;
                }
            }
        }
    }
}

// edge2csr: one wave per node, single pass.  16 edges/instr, float4 store.
__global__ __launch_bounds__(256) void edge2csr(const unsigned int* __restrict__ packed,
                                                const int* __restrict__ rowptr,
                                                const unsigned short* __restrict__ z,
                                                const float* __restrict__ bias2,
                                                float* __restrict__ out) {
    __shared__ unsigned int ebuf[4 * 64];
    __shared__ float vbuf[4 * 64];
    int wave = threadIdx.x >> 6, lane = threadIdx.x & 63;
    int f = blockIdx.x * 4 + wave;
    if (f >= N_NODES) return;
    int s = rowptr[f], k = rowptr[f + 1] - s;
    int sub = lane & 3, p = lane >> 2;
    f32x4 acc = {0.f, 0.f, 0.f, 0.f};
    for (int base = 0; base < k; base += 64) {
        int e = base + lane;
        if (e < k) {
            unsigned int pk = packed[s + e];
            ebuf[wave * 64 + lane] = pk;
            vbuf[wave * 64 + lane] = 1.0f / (float)(pk >> 22);
        }
        int cnum = min(64, k - base);
        int nst = (cnum + 15) >> 4;
#pragma unroll 4
        for (int i = 0; i < nst; i++) {
            int ei = (i << 4) + p;
            if (ei < cnum) {
                unsigned int pk = ebuf[wave * 64 + ei];
                float v = vbuf[wave * 64 + ei];
                int t_ = pk & 0x1FFFF, r = (pk >> 17) & 31;
                ushort4 raw = *(const ushort4*)(z + (size_t)t_ * 512 + (r << 4) + (sub << 2));
                acc.x += v * b2f(raw.x); acc.y += v * b2f(raw.y);
                acc.z += v * b2f(raw.z); acc.w += v * b2f(raw.w);
            }
        }
    }
#pragma unroll
    for (int ofs = 4; ofs < 64; ofs <<= 1) {
        acc.x += __shfl_xor(acc.x, ofs, 64);
        acc.y += __shfl_xor(acc.y, ofs, 64);
        acc.z += __shfl_xor(acc.z, ofs, 64);
        acc.w += __shfl_xor(acc.w, ofs, 64);
    }
    if (p == 0) {
        int c = sub << 2;
        float4 o;
        o.x = acc.x + bias2[c + 0];
        o.y = acc.y + bias2[c + 1];
        o.z = acc.z + bias2[c + 2];
        o.w = acc.w + bias2[c + 3];
        *(float4*)(out + (size_t)f * 16 + c) = o;
    }
}

extern "C" void kernel_launch(void* const* d_in, const int* in_sizes, int n_in,
                              void* d_out, int out_size, void* d_ws, size_t ws_size,
                              hipStream_t stream) {
    (void)in_sizes; (void)n_in; (void)out_size; (void)ws_size;
    const float* emb    = (const float*)d_in[0];
    const float* comps1 = (const float*)d_in[1];
    const float* bases1 = (const float*)d_in[2];
    const float* comps2 = (const float*)d_in[3];
    const float* bases2 = (const float*)d_in[4];
    const float* bias1  = (const float*)d_in[5];
    const float* bias2  = (const float*)d_in[6];
    const int* rel = (const int*)d_in[7];
    const int* fr  = (const int*)d_in[8];
    const int* to  = (const int*)d_in[9];
    float* out = (float*)d_out;
    char* ws = (char*)d_ws;

    // workspace layout (bytes); total ~250.3 MB
    int* gCursor         = (int*)(ws);                        // 1,568
    int* bucketBase      = (int*)(ws + 2048);                 // 1,568
    int* rowptr          = (int*)(ws + 4096);                 // 401,412
    unsigned int* packed = (unsigned int*)(ws + 406528);      // 12,800,000
    unsigned short* h1b  = (unsigned short*)(ws + 13206528);  // 6,406,144 (N_PAD x 32)
    unsigned short* w1T  = (unsigned short*)(ws + 19612672);  // 262,144
    unsigned short* w2T  = (unsigned short*)(ws + 19874816);  // 32,768
    unsigned short* embb = (unsigned short*)(ws + 19907584);  // 25,624,576 (N_PAD x 128)
    unsigned short* xw   = (unsigned short*)(ws + 45532160);  // 204,800,000
    unsigned short* z    = xw;                 // alias: xw dead before gemm2
    unsigned int* stage  = (unsigned int*)xw;  // alias: stage dead before gemm1

    kcur<<<2, 256, 0, stream>>>(gCursor);
    kemb<<<6256, 256, 0, stream>>>(emb, embb);
    kw1<<<512, 256, 0, stream>>>(comps1, bases1, w1T);
    kw2<<<64, 256, 0, stream>>>(comps2, bases2, w2T);
    kbinA<<<196, 256, 0, stream>>>(rel, fr, to, gCursor, stage);
    kscan<<<1, 512, 0, stream>>>(gCursor, bucketBase);
    kscatter2<<<NB, 256, 0, stream>>>(stage, gCursor, bucketBase, rowptr, packed);
    gemm1<<<1664, 256, 0, stream>>>(embb, w1T, xw);    // 8 xcd * 16 bn * 13 mgl
    edge1csr<<<25000, 256, 0, stream>>>(packed, rowptr, xw, bias1, h1b);
    gemm2<<<832, 256, 0, stream>>>(h1b, w2T, z);       // 8 xcd * 8 bn * 13 mgl
    edge2csr<<<25000, 256, 0, stream>>>(packed, rowptr, z, bias2, out);
}

// Round 8
// 494.745 us; speedup vs baseline: 6.7714x; 1.0579x over previous
//
#include <hip/hip_runtime.h>

// RGCN embedding, MI355X.  R8: kbinA re-gridded for occupancy (EPB 16384->2048,
// int4 edge loads); kscatter2 uint4 stage loads.  Rest unchanged from R7:
// streaming-wave GEMMs (B-slab in regs, ping-pong A prefetch, XCD swizzle),
// atomic-free CSR edge passes with deg packed into the edge word.
#define N_NODES 100000
#define N_PAD   100096
#define E_EDGES 3200000
#define NB      392            // buckets of 256 nodes
#define BCAP    12288
#define EPB     2048           // edges per kbinA block (1563 blocks ~ 6/CU)

typedef float f32x4 __attribute__((ext_vector_type(4)));
typedef __bf16 bf16x8 __attribute__((ext_vector_type(8)));

__device__ __forceinline__ float b2f(unsigned int u) {
    union { unsigned int i; float f; } x; x.i = u << 16; return x.f;
}
__device__ __forceinline__ unsigned short f2b(float f) {
    union { float f; unsigned int i; } x; x.f = f;
    unsigned int u = x.i + 0x7FFFu + ((x.i >> 16) & 1u);
    return (unsigned short)(u >> 16);
}

__global__ __launch_bounds__(256) void kcur(int* __restrict__ gCursor) {
    int id = blockIdx.x * 256 + threadIdx.x;
    if (id < NB) gCursor[id] = id * BCAP;
}

// emb f32 -> bf16, padded to N_PAD rows (pad = 0)
__global__ __launch_bounds__(256) void kemb(const float* __restrict__ emb,
                                            unsigned short* __restrict__ embb) {
    int id = blockIdx.x * 256 + threadIdx.x;
    if (id >= N_PAD * 128 / 8) return;
    size_t base = (size_t)id * 8;
    ushort4 o0 = {0, 0, 0, 0}, o1 = {0, 0, 0, 0};
    if (base < (size_t)N_NODES * 128) {
        float4 v0 = *(const float4*)(emb + base);
        float4 v1 = *(const float4*)(emb + base + 4);
        o0.x = f2b(v0.x); o0.y = f2b(v0.y); o0.z = f2b(v0.z); o0.w = f2b(v0.w);
        o1.x = f2b(v1.x); o1.y = f2b(v1.y); o1.z = f2b(v1.z); o1.w = f2b(v1.w);
    }
    *(ushort4*)(embb + base) = o0;
    *(ushort4*)(embb + base + 4) = o1;
}

// w1T[j][k] = sum_b comps1[r,b]*bases1[b,k,h], j=r*32+h  (bf16, [1024][128])
__global__ __launch_bounds__(256) void kw1(const float* __restrict__ comps1,
                                           const float* __restrict__ bases1,
                                           unsigned short* __restrict__ w1T) {
    int id = blockIdx.x * 256 + threadIdx.x;
    if (id >= 1024 * 128) return;
    int k = id & 127, j = id >> 7;
    int r = j >> 5, h = j & 31;
    float s = 0.f;
#pragma unroll
    for (int b = 0; b < 16; b++)
        s += comps1[r * 16 + b] * bases1[b * 4096 + k * 32 + h];
    w1T[(size_t)j * 128 + k] = f2b(s);
}

// w2T[j2][h] = sum_b comps2[r,b]*bases2[b,h,c], j2=r*16+c  (bf16, [512][32])
__global__ __launch_bounds__(256) void kw2(const float* __restrict__ comps2,
                                           const float* __restrict__ bases2,
                                           unsigned short* __restrict__ w2T) {
    int id = blockIdx.x * 256 + threadIdx.x;
    if (id >= 512 * 32) return;
    int h = id & 31, j = id >> 5;
    int r = j >> 4, c = j & 15;
    float s = 0.f;
#pragma unroll
    for (int b = 0; b < 16; b++)
        s += comps2[r * 16 + b] * bases2[b * 512 + h * 16 + c];
    w2T[(size_t)j * 32 + h] = f2b(s);
}

// Bin edges by fr>>8 into per-bucket stage regions.  word=(frlo<<22)|(rel<<17)|to.
// EPB=2048: 8 edges/thread via 2x int4 loads; LDS count -> coalesced cursor
// claim -> int4 reload + scatter into per-block contiguous runs.
__global__ __launch_bounds__(256) void kbinA(const int* __restrict__ rel,
                                             const int* __restrict__ fr,
                                             const int* __restrict__ to,
                                             int* __restrict__ gCursor,
                                             unsigned int* __restrict__ stage) {
    __shared__ int cnt[NB];
    __shared__ int base[NB];
    int tid = threadIdx.x;
    int g0 = blockIdx.x * (EPB / 4);            // int4-group base
    for (int i = tid; i < NB; i += 256) cnt[i] = 0;
    __syncthreads();
#pragma unroll
    for (int i = 0; i < EPB / 1024; i++) {
        int g = g0 + i * 256 + tid;
        if (g < E_EDGES / 4) {
            int4 f4 = ((const int4*)fr)[g];
            atomicAdd(&cnt[f4.x >> 8], 1);
            atomicAdd(&cnt[f4.y >> 8], 1);
            atomicAdd(&cnt[f4.z >> 8], 1);
            atomicAdd(&cnt[f4.w >> 8], 1);
        }
    }
    __syncthreads();
    for (int i = tid; i < NB; i += 256) {
        base[i] = atomicAdd(&gCursor[i], cnt[i]);
        cnt[i] = 0;
    }
    __syncthreads();
#pragma unroll
    for (int i = 0; i < EPB / 1024; i++) {
        int g = g0 + i * 256 + tid;
        if (g < E_EDGES / 4) {
            int4 f4 = ((const int4*)fr)[g];
            int4 r4 = ((const int4*)rel)[g];
            int4 t4 = ((const int4*)to)[g];
            int fa[4] = {f4.x, f4.y, f4.z, f4.w};
            int ra[4] = {r4.x, r4.y, r4.z, r4.w};
            int ta[4] = {t4.x, t4.y, t4.z, t4.w};
#pragma unroll
            for (int u = 0; u < 4; u++) {
                int b = fa[u] >> 8;
                int rank = atomicAdd(&cnt[b], 1);
                stage[base[b] + rank] =
                    ((unsigned int)(fa[u] & 255) << 22) | ((unsigned int)ra[u] << 17) | (unsigned int)ta[u];
            }
        }
    }
}

// exclusive scan of bucket counts -> bucketBase
__global__ __launch_bounds__(512) void kscan(const int* __restrict__ gCursor,
                                             int* __restrict__ bucketBase) {
    __shared__ int a[512], b[512];
    int t = threadIdx.x;
    int v = (t < NB) ? (gCursor[t] - t * BCAP) : 0;
    a[t] = v;
    __syncthreads();
    int* src = a; int* dst = b;
    for (int ofs = 1; ofs < 512; ofs <<= 1) {
        int x = src[t];
        if (t >= ofs) x += src[t - ofs];
        __syncthreads();
        dst[t] = x;
        __syncthreads();
        int* tmp = src; src = dst; dst = tmp;
    }
    if (t < NB) bucketBase[t] = src[t] - v;
}

// Per-bucket: LDS node-hist -> scan -> rowptr; (node,rel)-hist -> deg;
// scatter packed = (deg<<22)|(rel<<17)|to.  uint4 stage loads (sbase 16B-aligned).
__global__ __launch_bounds__(256) void kscatter2(const unsigned int* __restrict__ stage,
                                                 const int* __restrict__ gCursor,
                                                 const int* __restrict__ bucketBase,
                                                 int* __restrict__ rowptr,
                                                 unsigned int* __restrict__ packed) {
    __shared__ int hist[256], hexcl[256], rk[256], sa[256], sb[256];
    __shared__ int hist2[256 * 32];
    int b = blockIdx.x, t = threadIdx.x;
    int nb = gCursor[b] - b * BCAP;
    int sbase = b * BCAP;
    int gbase = bucketBase[b];
    int nb4 = nb >> 2;
    hist[t] = 0; rk[t] = 0;
    for (int i = t; i < 256 * 32; i += 256) hist2[i] = 0;
    __syncthreads();
    for (int i4 = t; i4 < nb4; i4 += 256) {
        uint4 p4 = ((const uint4*)(stage + sbase))[i4];
        unsigned int pa[4] = {p4.x, p4.y, p4.z, p4.w};
#pragma unroll
        for (int u = 0; u < 4; u++) {
            atomicAdd(&hist[pa[u] >> 22], 1);
            atomicAdd(&hist2[((pa[u] >> 22) << 5) | ((pa[u] >> 17) & 31)], 1);
        }
    }
    for (int i = (nb4 << 2) + t; i < nb; i += 256) {
        unsigned int pk = stage[sbase + i];
        atomicAdd(&hist[pk >> 22], 1);
        atomicAdd(&hist2[((pk >> 22) << 5) | ((pk >> 17) & 31)], 1);
    }
    __syncthreads();
    int v = hist[t];
    sa[t] = v;
    __syncthreads();
    int* src = sa; int* dst = sb;
    for (int ofs = 1; ofs < 256; ofs <<= 1) {
        int x = src[t];
        if (t >= ofs) x += src[t - ofs];
        __syncthreads();
        dst[t] = x;
        __syncthreads();
        int* tmp = src; src = dst; dst = tmp;
    }
    int excl = src[t] - v;
    hexcl[t] = excl;
    rowptr[b * 256 + t] = gbase + excl;
    __syncthreads();
    for (int i4 = t; i4 < nb4; i4 += 256) {
        uint4 p4 = ((const uint4*)(stage + sbase))[i4];
        unsigned int pa[4] = {p4.x, p4.y, p4.z, p4.w};
#pragma unroll
        for (int u = 0; u < 4; u++) {
            int frlo = pa[u] >> 22;
            int rank = atomicAdd(&rk[frlo], 1);
            int dg = min(hist2[(frlo << 5) | ((pa[u] >> 17) & 31)], 1023);
            packed[gbase + hexcl[frlo] + rank] = ((unsigned int)dg << 22) | (pa[u] & 0x3FFFFFu);
        }
    }
    for (int i = (nb4 << 2) + t; i < nb; i += 256) {
        unsigned int pk = stage[sbase + i];
        int frlo = pk >> 22;
        int rank = atomicAdd(&rk[frlo], 1);
        int dg = min(hist2[(frlo << 5) | ((pk >> 17) & 31)], 1023);
        packed[gbase + hexcl[frlo] + rank] = ((unsigned int)dg << 22) | (pk & 0x3FFFFFu);
    }
}

// GEMM1 (streaming-wave): xw[m][j] = sum_k embb[m][k]*w1T[j][k].
// Wave: B-slab 64n x 128k resident (16 frags); 16 m-iters of 16 rows each
// with ping-pong A prefetch.  Grid keeps an m-group's 16 bn-blocks on one XCD.
__global__ __launch_bounds__(256) void gemm1(const unsigned short* __restrict__ embb,
                                             const unsigned short* __restrict__ w1T,
                                             unsigned short* __restrict__ xw) {
    int id = blockIdx.x;
    int xcd = id & 7, w = id >> 3;
    int bn = w & 15, mgl = w >> 4;
    int mg = mgl * 8 + xcd;
    if (mg >= 98) return;
    int lane = threadIdx.x & 63, wave = threadIdx.x >> 6;
    int m_ = lane & 15, q = lane >> 4;
    bf16x8 B[4][4];
    const unsigned short* Bbase = w1T + (size_t)(bn * 64 + m_) * 128 + q * 8;
#pragma unroll
    for (int j = 0; j < 4; j++)
#pragma unroll
        for (int k0 = 0; k0 < 4; k0++)
            B[j][k0] = *(const bf16x8*)(Bbase + j * 16 * 128 + k0 * 32);
    int mrow0 = mg * 1024 + wave * 16;
    const unsigned short* Abase = embb + (size_t)(mrow0 + m_) * 128 + q * 8;
    bf16x8 a0[4], a1[4];
    if (mrow0 < N_PAD) {
#pragma unroll
        for (int k0 = 0; k0 < 4; k0++)
            a0[k0] = *(const bf16x8*)(Abase + k0 * 32);
    }
#pragma unroll
    for (int t = 0; t < 16; t++) {
        int m0 = mrow0 + t * 64;
        if (m0 >= N_PAD) break;
        bf16x8* acur = (t & 1) ? a1 : a0;
        bf16x8* anext = (t & 1) ? a0 : a1;
        if (t < 15 && m0 + 64 < N_PAD) {
#pragma unroll
            for (int k0 = 0; k0 < 4; k0++)
                anext[k0] = *(const bf16x8*)(Abase + (size_t)(t + 1) * 64 * 128 + k0 * 32);
        }
        f32x4 acc[4] = {};
#pragma unroll
        for (int k0 = 0; k0 < 4; k0++)
#pragma unroll
            for (int j = 0; j < 4; j++)
                acc[j] = __builtin_amdgcn_mfma_f32_16x16x32_bf16(B[j][k0], acur[k0], acc[j], 0, 0, 0);
        int grow = m0 + m_;
        if (grow < N_NODES) {
#pragma unroll
            for (int j = 0; j < 4; j++) {
                ushort4 s;
                s.x = f2b(acc[j][0]); s.y = f2b(acc[j][1]);
                s.z = f2b(acc[j][2]); s.w = f2b(acc[j][3]);
                *(ushort4*)(xw + (size_t)grow * 1024 + bn * 64 + j * 16 + q * 4) = s;
            }
        }
    }
}

// edge1csr: one wave per node, single pass (deg packed).  8 edges/instr.
__global__ __launch_bounds__(256) void edge1csr(const unsigned int* __restrict__ packed,
                                                const int* __restrict__ rowptr,
                                                const unsigned short* __restrict__ xw,
                                                const float* __restrict__ bias1,
                                                unsigned short* __restrict__ h1b) {
    __shared__ unsigned int ebuf[4 * 64];
    __shared__ float vbuf[4 * 64];
    int wave = threadIdx.x >> 6, lane = threadIdx.x & 63;
    int f = blockIdx.x * 4 + wave;
    if (f >= N_NODES) return;
    int s = rowptr[f], k = rowptr[f + 1] - s;
    int sub = lane & 7, p = lane >> 3;
    f32x4 acc = {0.f, 0.f, 0.f, 0.f};
    for (int base = 0; base < k; base += 64) {
        int e = base + lane;
        if (e < k) {
            unsigned int pk = packed[s + e];
            ebuf[wave * 64 + lane] = pk;
            vbuf[wave * 64 + lane] = 1.0f / (float)(pk >> 22);
        }
        int cnum = min(64, k - base);
        int nst = (cnum + 7) >> 3;
#pragma unroll 4
        for (int i = 0; i < nst; i++) {
            int ei = (i << 3) + p;
            if (ei < cnum) {
                unsigned int pk = ebuf[wave * 64 + ei];
                float v = vbuf[wave * 64 + ei];
                int t_ = pk & 0x1FFFF, r = (pk >> 17) & 31;
                ushort4 raw = *(const ushort4*)(xw + (size_t)t_ * 1024 + (r << 5) + (sub << 2));
                acc.x += v * b2f(raw.x); acc.y += v * b2f(raw.y);
                acc.z += v * b2f(raw.z); acc.w += v * b2f(raw.w);
            }
        }
    }
#pragma unroll
    for (int ofs = 8; ofs < 64; ofs <<= 1) {
        acc.x += __shfl_xor(acc.x, ofs, 64);
        acc.y += __shfl_xor(acc.y, ofs, 64);
        acc.z += __shfl_xor(acc.z, ofs, 64);
        acc.w += __shfl_xor(acc.w, ofs, 64);
    }
    if (p == 0) {
        int h = sub << 2;
        ushort4 o;
        o.x = f2b(fmaxf(acc.x + bias1[h + 0], 0.f));
        o.y = f2b(fmaxf(acc.y + bias1[h + 1], 0.f));
        o.z = f2b(fmaxf(acc.z + bias1[h + 2], 0.f));
        o.w = f2b(fmaxf(acc.w + bias1[h + 3], 0.f));
        *(ushort4*)(h1b + (size_t)f * 32 + h) = o;
    }
}

// GEMM2 (streaming-wave): z[m][j2] = sum_h h1b[m][h]*w2T[j2][h].  K=32.
__global__ __launch_bounds__(256) void gemm2(const unsigned short* __restrict__ h1b,
                                             const unsigned short* __restrict__ w2T,
                                             unsigned short* __restrict__ z) {
    int id = blockIdx.x;
    int xcd = id & 7, w = id >> 3;
    int bn = w & 7, mgl = w >> 3;
    int mg = mgl * 8 + xcd;
    if (mg >= 98) return;
    int lane = threadIdx.x & 63, wave = threadIdx.x >> 6;
    int m_ = lane & 15, q = lane >> 4;
    bf16x8 B[4];
    const unsigned short* Bbase = w2T + (size_t)(bn * 64 + m_) * 32 + q * 8;
#pragma unroll
    for (int j = 0; j < 4; j++)
        B[j] = *(const bf16x8*)(Bbase + j * 16 * 32);
    int mrow0 = mg * 1024 + wave * 32;
    const unsigned short* Abase = h1b + (size_t)(mrow0 + m_) * 32 + q * 8;
    bf16x8 a0[2], a1[2];
    if (mrow0 < N_PAD) {
        a0[0] = *(const bf16x8*)(Abase);
        a0[1] = *(const bf16x8*)(Abase + 16 * 32);
    }
#pragma unroll
    for (int t = 0; t < 8; t++) {
        int m0 = mrow0 + t * 128;
        if (m0 >= N_PAD) break;
        bf16x8* acur = (t & 1) ? a1 : a0;
        bf16x8* anext = (t & 1) ? a0 : a1;
        if (t < 7 && m0 + 128 < N_PAD) {
            anext[0] = *(const bf16x8*)(Abase + (size_t)(t + 1) * 128 * 32);
            anext[1] = *(const bf16x8*)(Abase + (size_t)(t + 1) * 128 * 32 + 16 * 32);
        }
        f32x4 acc[2][4] = {};
#pragma unroll
        for (int i = 0; i < 2; i++)
#pragma unroll
            for (int j = 0; j < 4; j++)
                acc[i][j] = __builtin_amdgcn_mfma_f32_16x16x32_bf16(B[j], acur[i], acc[i][j], 0, 0, 0);
#pragma unroll
        for (int i = 0; i < 2; i++) {
            int grow = m0 + i * 16 + m_;
            if (grow < N_NODES) {
#pragma unroll
                for (int j = 0; j < 4; j++) {
                    ushort4 s;
                    s.x = f2b(acc[i][j][0]); s.y = f2b(acc[i][j][1]);
                    s.z = f2b(acc[i][j][2]); s.w = f2b(acc[i][j][3]);
                    *(ushort4*)(z + (size_t)grow * 512 + bn * 64 + j * 16 + q * 4) = s;
                }
            }
        }
    }
}

// edge2csr: one wave per node, single pass.  16 edges/instr, float4 store.
__global__ __launch_bounds__(256) void edge2csr(const unsigned int* __restrict__ packed,
                                                const int* __restrict__ rowptr,
                                                const unsigned short* __restrict__ z,
                                                const float* __restrict__ bias2,
                                                float* __restrict__ out) {
    __shared__ unsigned int ebuf[4 * 64];
    __shared__ float vbuf[4 * 64];
    int wave = threadIdx.x >> 6, lane = threadIdx.x & 63;
    int f = blockIdx.x * 4 + wave;
    if (f >= N_NODES) return;
    int s = rowptr[f], k = rowptr[f + 1] - s;
    int sub = lane & 3, p = lane >> 2;
    f32x4 acc = {0.f, 0.f, 0.f, 0.f};
    for (int base = 0; base < k; base += 64) {
        int e = base + lane;
        if (e < k) {
            unsigned int pk = packed[s + e];
            ebuf[wave * 64 + lane] = pk;
            vbuf[wave * 64 + lane] = 1.0f / (float)(pk >> 22);
        }
        int cnum = min(64, k - base);
        int nst = (cnum + 15) >> 4;
#pragma unroll 4
        for (int i = 0; i < nst; i++) {
            int ei = (i << 4) + p;
            if (ei < cnum) {
                unsigned int pk = ebuf[wave * 64 + ei];
                float v = vbuf[wave * 64 + ei];
                int t_ = pk & 0x1FFFF, r = (pk >> 17) & 31;
                ushort4 raw = *(const ushort4*)(z + (size_t)t_ * 512 + (r << 4) + (sub << 2));
                acc.x += v * b2f(raw.x); acc.y += v * b2f(raw.y);
                acc.z += v * b2f(raw.z); acc.w += v * b2f(raw.w);
            }
        }
    }
#pragma unroll
    for (int ofs = 4; ofs < 64; ofs <<= 1) {
        acc.x += __shfl_xor(acc.x, ofs, 64);
        acc.y += __shfl_xor(acc.y, ofs, 64);
        acc.z += __shfl_xor(acc.z, ofs, 64);
        acc.w += __shfl_xor(acc.w, ofs, 64);
    }
    if (p == 0) {
        int c = sub << 2;
        float4 o;
        o.x = acc.x + bias2[c + 0];
        o.y = acc.y + bias2[c + 1];
        o.z = acc.z + bias2[c + 2];
        o.w = acc.w + bias2[c + 3];
        *(float4*)(out + (size_t)f * 16 + c) = o;
    }
}

extern "C" void kernel_launch(void* const* d_in, const int* in_sizes, int n_in,
                              void* d_out, int out_size, void* d_ws, size_t ws_size,
                              hipStream_t stream) {
    (void)in_sizes; (void)n_in; (void)out_size; (void)ws_size;
    const float* emb    = (const float*)d_in[0];
    const float* comps1 = (const float*)d_in[1];
    const float* bases1 = (const float*)d_in[2];
    const float* comps2 = (const float*)d_in[3];
    const float* bases2 = (const float*)d_in[4];
    const float* bias1  = (const float*)d_in[5];
    const float* bias2  = (const float*)d_in[6];
    const int* rel = (const int*)d_in[7];
    const int* fr  = (const int*)d_in[8];
    const int* to  = (const int*)d_in[9];
    float* out = (float*)d_out;
    char* ws = (char*)d_ws;

    // workspace layout (bytes); total ~250.3 MB
    int* gCursor         = (int*)(ws);                        // 1,568
    int* bucketBase      = (int*)(ws + 2048);                 // 1,568
    int* rowptr          = (int*)(ws + 4096);                 // 401,412
    unsigned int* packed = (unsigned int*)(ws + 406528);      // 12,800,000
    unsigned short* h1b  = (unsigned short*)(ws + 13206528);  // 6,406,144 (N_PAD x 32)
    unsigned short* w1T  = (unsigned short*)(ws + 19612672);  // 262,144
    unsigned short* w2T  = (unsigned short*)(ws + 19874816);  // 32,768
    unsigned short* embb = (unsigned short*)(ws + 19907584);  // 25,624,576 (N_PAD x 128)
    unsigned short* xw   = (unsigned short*)(ws + 45532160);  // 204,800,000
    unsigned short* z    = xw;                 // alias: xw dead before gemm2
    unsigned int* stage  = (unsigned int*)xw;  // alias: stage dead before gemm1

    kcur<<<2, 256, 0, stream>>>(gCursor);
    kemb<<<6256, 256, 0, stream>>>(emb, embb);
    kw1<<<512, 256, 0, stream>>>(comps1, bases1, w1T);
    kw2<<<64, 256, 0, stream>>>(comps2, bases2, w2T);
    kbinA<<<(E_EDGES + EPB - 1) / EPB, 256, 0, stream>>>(rel, fr, to, gCursor, stage);
    kscan<<<1, 512, 0, stream>>>(gCursor, bucketBase);
    kscatter2<<<NB, 256, 0, stream>>>(stage, gCursor, bucketBase, rowptr, packed);
    gemm1<<<1664, 256, 0, stream>>>(embb, w1T, xw);    // 8 xcd * 16 bn * 13 mgl
    edge1csr<<<25000, 256, 0, stream>>>(packed, rowptr, xw, bias1, h1b);
    gemm2<<<832, 256, 0, stream>>>(h1b, w2T, z);       // 8 xcd * 8 bn * 13 mgl
    edge2csr<<<25000, 256, 0, stream>>>(packed, rowptr, z, bias2, out);
}

// Round 9
// 462.700 us; speedup vs baseline: 7.2403x; 1.0693x over previous
//
#include <hip/hip_runtime.h>

// RGCN embedding, MI355X.  R9: LDS-pack epilogues in both GEMMs — wave packs
// its 16x64 output tile through padded wave-private LDS, then stores 1KB
// contiguous (8 full 128B lines per instr) instead of 16 partial lines per
// ushort4 store.  Rest unchanged from R8.
#define N_NODES 100000
#define N_PAD   100096
#define E_EDGES 3200000
#define NB      392            // buckets of 256 nodes
#define BCAP    12288
#define EPB     2048           // edges per kbinA block

typedef float f32x4 __attribute__((ext_vector_type(4)));
typedef __bf16 bf16x8 __attribute__((ext_vector_type(8)));

__device__ __forceinline__ float b2f(unsigned int u) {
    union { unsigned int i; float f; } x; x.i = u << 16; return x.f;
}
__device__ __forceinline__ unsigned short f2b(float f) {
    union { float f; unsigned int i; } x; x.f = f;
    unsigned int u = x.i + 0x7FFFu + ((x.i >> 16) & 1u);
    return (unsigned short)(u >> 16);
}

__global__ __launch_bounds__(256) void kcur(int* __restrict__ gCursor) {
    int id = blockIdx.x * 256 + threadIdx.x;
    if (id < NB) gCursor[id] = id * BCAP;
}

// emb f32 -> bf16, padded to N_PAD rows (pad = 0)
__global__ __launch_bounds__(256) void kemb(const float* __restrict__ emb,
                                            unsigned short* __restrict__ embb) {
    int id = blockIdx.x * 256 + threadIdx.x;
    if (id >= N_PAD * 128 / 8) return;
    size_t base = (size_t)id * 8;
    ushort4 o0 = {0, 0, 0, 0}, o1 = {0, 0, 0, 0};
    if (base < (size_t)N_NODES * 128) {
        float4 v0 = *(const float4*)(emb + base);
        float4 v1 = *(const float4*)(emb + base + 4);
        o0.x = f2b(v0.x); o0.y = f2b(v0.y); o0.z = f2b(v0.z); o0.w = f2b(v0.w);
        o1.x = f2b(v1.x); o1.y = f2b(v1.y); o1.z = f2b(v1.z); o1.w = f2b(v1.w);
    }
    *(ushort4*)(embb + base) = o0;
    *(ushort4*)(embb + base + 4) = o1;
}

// w1T[j][k] = sum_b comps1[r,b]*bases1[b,k,h], j=r*32+h  (bf16, [1024][128])
__global__ __launch_bounds__(256) void kw1(const float* __restrict__ comps1,
                                           const float* __restrict__ bases1,
                                           unsigned short* __restrict__ w1T) {
    int id = blockIdx.x * 256 + threadIdx.x;
    if (id >= 1024 * 128) return;
    int k = id & 127, j = id >> 7;
    int r = j >> 5, h = j & 31;
    float s = 0.f;
#pragma unroll
    for (int b = 0; b < 16; b++)
        s += comps1[r * 16 + b] * bases1[b * 4096 + k * 32 + h];
    w1T[(size_t)j * 128 + k] = f2b(s);
}

// w2T[j2][h] = sum_b comps2[r,b]*bases2[b,h,c], j2=r*16+c  (bf16, [512][32])
__global__ __launch_bounds__(256) void kw2(const float* __restrict__ comps2,
                                           const float* __restrict__ bases2,
                                           unsigned short* __restrict__ w2T) {
    int id = blockIdx.x * 256 + threadIdx.x;
    if (id >= 512 * 32) return;
    int h = id & 31, j = id >> 5;
    int r = j >> 4, c = j & 15;
    float s = 0.f;
#pragma unroll
    for (int b = 0; b < 16; b++)
        s += comps2[r * 16 + b] * bases2[b * 512 + h * 16 + c];
    w2T[(size_t)j * 32 + h] = f2b(s);
}

// Bin edges by fr>>8 into per-bucket stage regions.  word=(frlo<<22)|(rel<<17)|to.
__global__ __launch_bounds__(256) void kbinA(const int* __restrict__ rel,
                                             const int* __restrict__ fr,
                                             const int* __restrict__ to,
                                             int* __restrict__ gCursor,
                                             unsigned int* __restrict__ stage) {
    __shared__ int cnt[NB];
    __shared__ int base[NB];
    int tid = threadIdx.x;
    int g0 = blockIdx.x * (EPB / 4);            // int4-group base
    for (int i = tid; i < NB; i += 256) cnt[i] = 0;
    __syncthreads();
#pragma unroll
    for (int i = 0; i < EPB / 1024; i++) {
        int g = g0 + i * 256 + tid;
        if (g < E_EDGES / 4) {
            int4 f4 = ((const int4*)fr)[g];
            atomicAdd(&cnt[f4.x >> 8], 1);
            atomicAdd(&cnt[f4.y >> 8], 1);
            atomicAdd(&cnt[f4.z >> 8], 1);
            atomicAdd(&cnt[f4.w >> 8], 1);
        }
    }
    __syncthreads();
    for (int i = tid; i < NB; i += 256) {
        base[i] = atomicAdd(&gCursor[i], cnt[i]);
        cnt[i] = 0;
    }
    __syncthreads();
#pragma unroll
    for (int i = 0; i < EPB / 1024; i++) {
        int g = g0 + i * 256 + tid;
        if (g < E_EDGES / 4) {
            int4 f4 = ((const int4*)fr)[g];
            int4 r4 = ((const int4*)rel)[g];
            int4 t4 = ((const int4*)to)[g];
            int fa[4] = {f4.x, f4.y, f4.z, f4.w};
            int ra[4] = {r4.x, r4.y, r4.z, r4.w};
            int ta[4] = {t4.x, t4.y, t4.z, t4.w};
#pragma unroll
            for (int u = 0; u < 4; u++) {
                int b = fa[u] >> 8;
                int rank = atomicAdd(&cnt[b], 1);
                stage[base[b] + rank] =
                    ((unsigned int)(fa[u] & 255) << 22) | ((unsigned int)ra[u] << 17) | (unsigned int)ta[u];
            }
        }
    }
}

// exclusive scan of bucket counts -> bucketBase
__global__ __launch_bounds__(512) void kscan(const int* __restrict__ gCursor,
                                             int* __restrict__ bucketBase) {
    __shared__ int a[512], b[512];
    int t = threadIdx.x;
    int v = (t < NB) ? (gCursor[t] - t * BCAP) : 0;
    a[t] = v;
    __syncthreads();
    int* src = a; int* dst = b;
    for (int ofs = 1; ofs < 512; ofs <<= 1) {
        int x = src[t];
        if (t >= ofs) x += src[t - ofs];
        __syncthreads();
        dst[t] = x;
        __syncthreads();
        int* tmp = src; src = dst; dst = tmp;
    }
    if (t < NB) bucketBase[t] = src[t] - v;
}

// Per-bucket: LDS node-hist -> scan -> rowptr; (node,rel)-hist -> deg;
// scatter packed = (deg<<22)|(rel<<17)|to.  uint4 stage loads.
__global__ __launch_bounds__(256) void kscatter2(const unsigned int* __restrict__ stage,
                                                 const int* __restrict__ gCursor,
                                                 const int* __restrict__ bucketBase,
                                                 int* __restrict__ rowptr,
                                                 unsigned int* __restrict__ packed) {
    __shared__ int hist[256], hexcl[256], rk[256], sa[256], sb[256];
    __shared__ int hist2[256 * 32];
    int b = blockIdx.x, t = threadIdx.x;
    int nb = gCursor[b] - b * BCAP;
    int sbase = b * BCAP;
    int gbase = bucketBase[b];
    int nb4 = nb >> 2;
    hist[t] = 0; rk[t] = 0;
    for (int i = t; i < 256 * 32; i += 256) hist2[i] = 0;
    __syncthreads();
    for (int i4 = t; i4 < nb4; i4 += 256) {
        uint4 p4 = ((const uint4*)(stage + sbase))[i4];
        unsigned int pa[4] = {p4.x, p4.y, p4.z, p4.w};
#pragma unroll
        for (int u = 0; u < 4; u++) {
            atomicAdd(&hist[pa[u] >> 22], 1);
            atomicAdd(&hist2[((pa[u] >> 22) << 5) | ((pa[u] >> 17) & 31)], 1);
        }
    }
    for (int i = (nb4 << 2) + t; i < nb; i += 256) {
        unsigned int pk = stage[sbase + i];
        atomicAdd(&hist[pk >> 22], 1);
        atomicAdd(&hist2[((pk >> 22) << 5) | ((pk >> 17) & 31)], 1);
    }
    __syncthreads();
    int v = hist[t];
    sa[t] = v;
    __syncthreads();
    int* src = sa; int* dst = sb;
    for (int ofs = 1; ofs < 256; ofs <<= 1) {
        int x = src[t];
        if (t >= ofs) x += src[t - ofs];
        __syncthreads();
        dst[t] = x;
        __syncthreads();
        int* tmp = src; src = dst; dst = tmp;
    }
    int excl = src[t] - v;
    hexcl[t] = excl;
    rowptr[b * 256 + t] = gbase + excl;
    __syncthreads();
    for (int i4 = t; i4 < nb4; i4 += 256) {
        uint4 p4 = ((const uint4*)(stage + sbase))[i4];
        unsigned int pa[4] = {p4.x, p4.y, p4.z, p4.w};
#pragma unroll
        for (int u = 0; u < 4; u++) {
            int frlo = pa[u] >> 22;
            int rank = atomicAdd(&rk[frlo], 1);
            int dg = min(hist2[(frlo << 5) | ((pa[u] >> 17) & 31)], 1023);
            packed[gbase + hexcl[frlo] + rank] = ((unsigned int)dg << 22) | (pa[u] & 0x3FFFFFu);
        }
    }
    for (int i = (nb4 << 2) + t; i < nb; i += 256) {
        unsigned int pk = stage[sbase + i];
        int frlo = pk >> 22;
        int rank = atomicAdd(&rk[frlo], 1);
        int dg = min(hist2[(frlo << 5) | ((pk >> 17) & 31)], 1023);
        packed[gbase + hexcl[frlo] + rank] = ((unsigned int)dg << 22) | (pk & 0x3FFFFFu);
    }
}

// GEMM1 (streaming-wave + LDS-pack epilogue): xw[m][j] = sum_k embb[m][k]*w1T[j][k].
// Wave: B-slab 64n x 128k resident; 16 m-iters of 16 rows, ping-pong A prefetch.
// Epilogue: acc tile -> wave-private LDS (136-short row stride) -> uint4 reads
// -> 2 stores/iter, each 8 fully-covered 128B lines.
__global__ __launch_bounds__(256) void gemm1(const unsigned short* __restrict__ embb,
                                             const unsigned short* __restrict__ w1T,
                                             unsigned short* __restrict__ xw) {
    __shared__ unsigned short ldsT[4 * 16 * 136];
    int id = blockIdx.x;
    int xcd = id & 7, w = id >> 3;
    int bn = w & 15, mgl = w >> 4;
    int mg = mgl * 8 + xcd;
    if (mg >= 98) return;
    int lane = threadIdx.x & 63, wave = threadIdx.x >> 6;
    int m_ = lane & 15, q = lane >> 4;
    unsigned short* tw = &ldsT[wave * 16 * 136];
    bf16x8 B[4][4];
    const unsigned short* Bbase = w1T + (size_t)(bn * 64 + m_) * 128 + q * 8;
#pragma unroll
    for (int j = 0; j < 4; j++)
#pragma unroll
        for (int k0 = 0; k0 < 4; k0++)
            B[j][k0] = *(const bf16x8*)(Bbase + j * 16 * 128 + k0 * 32);
    int mrow0 = mg * 1024 + wave * 16;
    const unsigned short* Abase = embb + (size_t)(mrow0 + m_) * 128 + q * 8;
    bf16x8 a0[4], a1[4];
    if (mrow0 < N_PAD) {
#pragma unroll
        for (int k0 = 0; k0 < 4; k0++)
            a0[k0] = *(const bf16x8*)(Abase + k0 * 32);
    }
#pragma unroll
    for (int t = 0; t < 16; t++) {
        int m0 = mrow0 + t * 64;
        if (m0 >= N_PAD) break;
        bf16x8* acur = (t & 1) ? a1 : a0;
        bf16x8* anext = (t & 1) ? a0 : a1;
        if (t < 15 && m0 + 64 < N_PAD) {
#pragma unroll
            for (int k0 = 0; k0 < 4; k0++)
                anext[k0] = *(const bf16x8*)(Abase + (size_t)(t + 1) * 64 * 128 + k0 * 32);
        }
        f32x4 acc[4] = {};
#pragma unroll
        for (int k0 = 0; k0 < 4; k0++)
#pragma unroll
            for (int j = 0; j < 4; j++)
                acc[j] = __builtin_amdgcn_mfma_f32_16x16x32_bf16(B[j][k0], acur[k0], acc[j], 0, 0, 0);
        // pack tile (rows m_, cols jj*16+q*4) into LDS
#pragma unroll
        for (int jj = 0; jj < 4; jj++) {
            ushort4 s;
            s.x = f2b(acc[jj][0]); s.y = f2b(acc[jj][1]);
            s.z = f2b(acc[jj][2]); s.w = f2b(acc[jj][3]);
            *(ushort4*)(tw + m_ * 136 + jj * 16 + q * 4) = s;
        }
        __asm__ volatile("s_waitcnt lgkmcnt(0)" ::: "memory");
#pragma unroll
        for (int ri = 0; ri < 2; ri++) {
            int row = (lane >> 3) + ri * 8;
            int c = lane & 7;
            uint4 v = *(const uint4*)(tw + row * 136 + c * 8);
            int grow = m0 + row;
            if (grow < N_NODES)
                *(uint4*)(xw + (size_t)grow * 1024 + bn * 64 + c * 8) = v;
        }
        __asm__ volatile("s_waitcnt lgkmcnt(0)" ::: "memory");
    }
}

// edge1csr: one wave per node, single pass (deg packed).  8 edges/instr.
__global__ __launch_bounds__(256) void edge1csr(const unsigned int* __restrict__ packed,
                                                const int* __restrict__ rowptr,
                                                const unsigned short* __restrict__ xw,
                                                const float* __restrict__ bias1,
                                                unsigned short* __restrict__ h1b) {
    __shared__ unsigned int ebuf[4 * 64];
    __shared__ float vbuf[4 * 64];
    int wave = threadIdx.x >> 6, lane = threadIdx.x & 63;
    int f = blockIdx.x * 4 + wave;
    if (f >= N_NODES) return;
    int s = rowptr[f], k = rowptr[f + 1] - s;
    int sub = lane & 7, p = lane >> 3;
    f32x4 acc = {0.f, 0.f, 0.f, 0.f};
    for (int base = 0; base < k; base += 64) {
        int e = base + lane;
        if (e < k) {
            unsigned int pk = packed[s + e];
            ebuf[wave * 64 + lane] = pk;
            vbuf[wave * 64 + lane] = 1.0f / (float)(pk >> 22);
        }
        int cnum = min(64, k - base);
        int nst = (cnum + 7) >> 3;
#pragma unroll 4
        for (int i = 0; i < nst; i++) {
            int ei = (i << 3) + p;
            if (ei < cnum) {
                unsigned int pk = ebuf[wave * 64 + ei];
                float v = vbuf[wave * 64 + ei];
                int t_ = pk & 0x1FFFF, r = (pk >> 17) & 31;
                ushort4 raw = *(const ushort4*)(xw + (size_t)t_ * 1024 + (r << 5) + (sub << 2));
                acc.x += v * b2f(raw.x); acc.y += v * b2f(raw.y);
                acc.z += v * b2f(raw.z); acc.w += v * b2f(raw.w);
            }
        }
    }
#pragma unroll
    for (int ofs = 8; ofs < 64; ofs <<= 1) {
        acc.x += __shfl_xor(acc.x, ofs, 64);
        acc.y += __shfl_xor(acc.y, ofs, 64);
        acc.z += __shfl_xor(acc.z, ofs, 64);
        acc.w += __shfl_xor(acc.w, ofs, 64);
    }
    if (p == 0) {
        int h = sub << 2;
        ushort4 o;
        o.x = f2b(fmaxf(acc.x + bias1[h + 0], 0.f));
        o.y = f2b(fmaxf(acc.y + bias1[h + 1], 0.f));
        o.z = f2b(fmaxf(acc.z + bias1[h + 2], 0.f));
        o.w = f2b(fmaxf(acc.w + bias1[h + 3], 0.f));
        *(ushort4*)(h1b + (size_t)f * 32 + h) = o;
    }
}

// GEMM2 (streaming-wave + LDS-pack epilogue): z[m][j2] = sum_h h1b[m][h]*w2T[j2][h].
__global__ __launch_bounds__(256) void gemm2(const unsigned short* __restrict__ h1b,
                                             const unsigned short* __restrict__ w2T,
                                             unsigned short* __restrict__ z) {
    __shared__ unsigned short ldsT[4 * 16 * 136];
    int id = blockIdx.x;
    int xcd = id & 7, w = id >> 3;
    int bn = w & 7, mgl = w >> 3;
    int mg = mgl * 8 + xcd;
    if (mg >= 98) return;
    int lane = threadIdx.x & 63, wave = threadIdx.x >> 6;
    int m_ = lane & 15, q = lane >> 4;
    unsigned short* tw = &ldsT[wave * 16 * 136];
    bf16x8 B[4];
    const unsigned short* Bbase = w2T + (size_t)(bn * 64 + m_) * 32 + q * 8;
#pragma unroll
    for (int j = 0; j < 4; j++)
        B[j] = *(const bf16x8*)(Bbase + j * 16 * 32);
    int mrow0 = mg * 1024 + wave * 32;
    const unsigned short* Abase = h1b + (size_t)(mrow0 + m_) * 32 + q * 8;
    bf16x8 a0[2], a1[2];
    if (mrow0 < N_PAD) {
        a0[0] = *(const bf16x8*)(Abase);
        a0[1] = *(const bf16x8*)(Abase + 16 * 32);
    }
#pragma unroll
    for (int t = 0; t < 8; t++) {
        int m0 = mrow0 + t * 128;
        if (m0 >= N_PAD) break;
        bf16x8* acur = (t & 1) ? a1 : a0;
        bf16x8* anext = (t & 1) ? a0 : a1;
        if (t < 7 && m0 + 128 < N_PAD) {
            anext[0] = *(const bf16x8*)(Abase + (size_t)(t + 1) * 128 * 32);
            anext[1] = *(const bf16x8*)(Abase + (size_t)(t + 1) * 128 * 32 + 16 * 32);
        }
        f32x4 acc[2][4] = {};
#pragma unroll
        for (int i = 0; i < 2; i++)
#pragma unroll
            for (int j = 0; j < 4; j++)
                acc[i][j] = __builtin_amdgcn_mfma_f32_16x16x32_bf16(B[j], acur[i], acc[i][j], 0, 0, 0);
#pragma unroll
        for (int i = 0; i < 2; i++) {
#pragma unroll
            for (int jj = 0; jj < 4; jj++) {
                ushort4 s;
                s.x = f2b(acc[i][jj][0]); s.y = f2b(acc[i][jj][1]);
                s.z = f2b(acc[i][jj][2]); s.w = f2b(acc[i][jj][3]);
                *(ushort4*)(tw + m_ * 136 + jj * 16 + q * 4) = s;
            }
            __asm__ volatile("s_waitcnt lgkmcnt(0)" ::: "memory");
#pragma unroll
            for (int ri = 0; ri < 2; ri++) {
                int row = (lane >> 3) + ri * 8;
                int c = lane & 7;
                uint4 v = *(const uint4*)(tw + row * 136 + c * 8);
                int grow = m0 + i * 16 + row;
                if (grow < N_NODES)
                    *(uint4*)(z + (size_t)grow * 512 + bn * 64 + c * 8) = v;
            }
            __asm__ volatile("s_waitcnt lgkmcnt(0)" ::: "memory");
        }
    }
}

// edge2csr: one wave per node, single pass.  16 edges/instr, float4 store.
__global__ __launch_bounds__(256) void edge2csr(const unsigned int* __restrict__ packed,
                                                const int* __restrict__ rowptr,
                                                const unsigned short* __restrict__ z,
                                                const float* __restrict__ bias2,
                                                float* __restrict__ out) {
    __shared__ unsigned int ebuf[4 * 64];
    __shared__ float vbuf[4 * 64];
    int wave = threadIdx.x >> 6, lane = threadIdx.x & 63;
    int f = blockIdx.x * 4 + wave;
    if (f >= N_NODES) return;
    int s = rowptr[f], k = rowptr[f + 1] - s;
    int sub = lane & 3, p = lane >> 2;
    f32x4 acc = {0.f, 0.f, 0.f, 0.f};
    for (int base = 0; base < k; base += 64) {
        int e = base + lane;
        if (e < k) {
            unsigned int pk = packed[s + e];
            ebuf[wave * 64 + lane] = pk;
            vbuf[wave * 64 + lane] = 1.0f / (float)(pk >> 22);
        }
        int cnum = min(64, k - base);
        int nst = (cnum + 15) >> 4;
#pragma unroll 4
        for (int i = 0; i < nst; i++) {
            int ei = (i << 4) + p;
            if (ei < cnum) {
                unsigned int pk = ebuf[wave * 64 + ei];
                float v = vbuf[wave * 64 + ei];
                int t_ = pk & 0x1FFFF, r = (pk >> 17) & 31;
                ushort4 raw = *(const ushort4*)(z + (size_t)t_ * 512 + (r << 4) + (sub << 2));
                acc.x += v * b2f(raw.x); acc.y += v * b2f(raw.y);
                acc.z += v * b2f(raw.z); acc.w += v * b2f(raw.w);
            }
        }
    }
#pragma unroll
    for (int ofs = 4; ofs < 64; ofs <<= 1) {
        acc.x += __shfl_xor(acc.x, ofs, 64);
        acc.y += __shfl_xor(acc.y, ofs, 64);
        acc.z += __shfl_xor(acc.z, ofs, 64);
        acc.w += __shfl_xor(acc.w, ofs, 64);
    }
    if (p == 0) {
        int c = sub << 2;
        float4 o;
        o.x = acc.x + bias2[c + 0];
        o.y = acc.y + bias2[c + 1];
        o.z = acc.z + bias2[c + 2];
        o.w = acc.w + bias2[c + 3];
        *(float4*)(out + (size_t)f * 16 + c) = o;
    }
}

extern "C" void kernel_launch(void* const* d_in, const int* in_sizes, int n_in,
                              void* d_out, int out_size, void* d_ws, size_t ws_size,
                              hipStream_t stream) {
    (void)in_sizes; (void)n_in; (void)out_size; (void)ws_size;
    const float* emb    = (const float*)d_in[0];
    const float* comps1 = (const float*)d_in[1];
    const float* bases1 = (const float*)d_in[2];
    const float* comps2 = (const float*)d_in[3];
    const float* bases2 = (const float*)d_in[4];
    const float* bias1  = (const float*)d_in[5];
    const float* bias2  = (const float*)d_in[6];
    const int* rel = (const int*)d_in[7];
    const int* fr  = (const int*)d_in[8];
    const int* to  = (const int*)d_in[9];
    float* out = (float*)d_out;
    char* ws = (char*)d_ws;

    // workspace layout (bytes); total ~250.3 MB
    int* gCursor         = (int*)(ws);                        // 1,568
    int* bucketBase      = (int*)(ws + 2048);                 // 1,568
    int* rowptr          = (int*)(ws + 4096);                 // 401,412
    unsigned int* packed = (unsigned int*)(ws + 406528);      // 12,800,000
    unsigned short* h1b  = (unsigned short*)(ws + 13206528);  // 6,406,144 (N_PAD x 32)
    unsigned short* w1T  = (unsigned short*)(ws + 19612672);  // 262,144
    unsigned short* w2T  = (unsigned short*)(ws + 19874816);  // 32,768
    unsigned short* embb = (unsigned short*)(ws + 19907584);  // 25,624,576 (N_PAD x 128)
    unsigned short* xw   = (unsigned short*)(ws + 45532160);  // 204,800,000
    unsigned short* z    = xw;                 // alias: xw dead before gemm2
    unsigned int* stage  = (unsigned int*)xw;  // alias: stage dead before gemm1

    kcur<<<2, 256, 0, stream>>>(gCursor);
    kemb<<<6256, 256, 0, stream>>>(emb, embb);
    kw1<<<512, 256, 0, stream>>>(comps1, bases1, w1T);
    kw2<<<64, 256, 0, stream>>>(comps2, bases2, w2T);
    kbinA<<<(E_EDGES + EPB - 1) / EPB, 256, 0, stream>>>(rel, fr, to, gCursor, stage);
    kscan<<<1, 512, 0, stream>>>(gCursor, bucketBase);
    kscatter2<<<NB, 256, 0, stream>>>(stage, gCursor, bucketBase, rowptr, packed);
    gemm1<<<1664, 256, 0, stream>>>(embb, w1T, xw);    // 8 xcd * 16 bn * 13 mgl
    edge1csr<<<25000, 256, 0, stream>>>(packed, rowptr, xw, bias1, h1b);
    gemm2<<<832, 256, 0, stream>>>(h1b, w2T, z);       // 8 xcd * 8 bn * 13 mgl
    edge2csr<<<25000, 256, 0, stream>>>(packed, rowptr, z, bias2, out);
}